// Round 2
// baseline (4953.746 us; speedup 1.0000x reference)
//
#include <hip/hip_runtime.h>
#include <math.h>

// Problem constants (from reference)
#define NB   4      // batch
#define NQL  2048   // queries
#define NKVL 2048   // keys/values
#define HN   8      // heads
#define DQK  160    // qk feature dim: 16 mv ch * 8 inner comps + 32 scalars
#define DV   288    // v feature dim: 16 mv ch * 16 comps + 32 scalars
#define QT   32     // q rows per block (attn)
#define KTL  64     // k cols per tile (attn)
#define QFP  164    // padded LDS row stride for q feats
#define KFP  164    // padded LDS row stride for k feats
#define PP   68     // padded LDS row stride for p tile

// Component tables:
// grade of each of the 16 PGA components
__constant__ int c_grade[16] = {0,1,1,1,1,2,2,2,2,2,2,3,3,3,3,4};
// the 8 components without e0 (used in the attention inner product)
__constant__ int c_inner[8]  = {0,2,3,4,8,9,10,14};
// e0-left-mult source component for each output component (-1 = none)
__constant__ int c_esrc[16]  = {-1,0,-1,-1,-1,2,3,4,-1,-1,-1,8,9,10,-1,14};
// basis index (y) of the e0 map feeding each output component
__constant__ int c_ey[16]    = {0,5,0,0,0,6,6,6,0,0,0,7,7,7,0,8};

// ---------------- K/V projection ----------------
// K features (160): only grade-diagonal terms (inner comps are never e0 targets).
// V features (288): all 16 comps incl. e0 terms, + 32 scalar outs.
__global__ __launch_bounds__(256) void proj_kv_kernel(
    const float* __restrict__ mv_kv, const float* __restrict__ s_kv,
    const float* __restrict__ kw_mv, const float* __restrict__ kw_s2mv, const float* __restrict__ kb_mv,
    const float* __restrict__ kw_mv2s, const float* __restrict__ kw_s2s, const float* __restrict__ kb_s,
    const float* __restrict__ vw_mv, const float* __restrict__ vw_s2mv, const float* __restrict__ vb_mv,
    const float* __restrict__ vw_mv2s, const float* __restrict__ vw_s2s, const float* __restrict__ vb_s,
    float* __restrict__ Kf, float* __restrict__ Vf)
{
  __shared__ float mvL[8*256];
  __shared__ float sL[8*32];
  int p0 = blockIdx.x * 8;
  for (int i = threadIdx.x; i < 8*256; i += 256) mvL[i] = mv_kv[(size_t)p0*256 + i];
  for (int i = threadIdx.x; i < 8*32;  i += 256) sL[i]  = s_kv[(size_t)p0*32 + i];
  __syncthreads();
  int lp = threadIdx.x >> 5;
  int j  = threadIdx.x & 31;
  const float* mv = mvL + lp*256;
  const float* s  = sL  + lp*32;
  size_t gp = (size_t)p0 + lp;
  for (int f = j; f < DQK + DV; f += 32) {
    float val = 0.f;
    if (f < DQK) {
      if (f < 128) {
        int c = f >> 3;
        int a = c_inner[f & 7];
        int y = c_grade[a];
        for (int ci = 0; ci < 16; ci++) val += kw_mv[(c*16+ci)*9 + y] * mv[ci*16 + a];
        if (a == 0) {
          for (int i2 = 0; i2 < 32; i2++) val += s[i2] * kw_s2mv[c*32 + i2];
          val += kb_mv[c];
        }
      } else {
        int si = f - 128;
        for (int ci = 0; ci < 16; ci++) val += mv[ci*16] * kw_mv2s[si*16 + ci];
        for (int i2 = 0; i2 < 32; i2++) val += s[i2] * kw_s2s[si*32 + i2];
        val += kb_s[si];
      }
      Kf[gp*DQK + f] = val;
    } else {
      int g = f - DQK;
      if (g < 256) {
        int c = g >> 4, a = g & 15;
        int y = c_grade[a];
        for (int ci = 0; ci < 16; ci++) val += vw_mv[(c*16+ci)*9 + y] * mv[ci*16 + a];
        int sa = c_esrc[a];
        if (sa >= 0) {
          int ey = c_ey[a];
          for (int ci = 0; ci < 16; ci++) val += vw_mv[(c*16+ci)*9 + ey] * mv[ci*16 + sa];
        }
        if (a == 0) {
          for (int i2 = 0; i2 < 32; i2++) val += s[i2] * vw_s2mv[c*32 + i2];
          val += vb_mv[c];
        }
      } else {
        int si = g - 256;
        for (int ci = 0; ci < 16; ci++) val += mv[ci*16] * vw_mv2s[si*16 + ci];
        for (int i2 = 0; i2 < 32; i2++) val += s[i2] * vw_s2s[si*32 + i2];
        val += vb_s[si];
      }
      Vf[gp*DV + g] = val;
    }
  }
}

// ---------------- Q projection ----------------
// Per position: 8 heads x 160 feats. Channel layout is channel-major, head-minor
// (o = c*H + h for mv, o = si*H + h for scalars) per the einops reshape.
__global__ __launch_bounds__(256) void proj_q_kernel(
    const float* __restrict__ mv_q, const float* __restrict__ s_q,
    const float* __restrict__ qw_mv, const float* __restrict__ qw_s2mv, const float* __restrict__ qb_mv,
    const float* __restrict__ qw_mv2s, const float* __restrict__ qw_s2s, const float* __restrict__ qb_s,
    float* __restrict__ Qf)
{
  __shared__ float mvL[4*256];
  __shared__ float sL[4*32];
  int p0 = blockIdx.x * 4;
  for (int i = threadIdx.x; i < 4*256; i += 256) mvL[i] = mv_q[(size_t)p0*256 + i];
  if (threadIdx.x < 4*32) sL[threadIdx.x] = s_q[(size_t)p0*32 + threadIdx.x];
  __syncthreads();
  int lp = threadIdx.x >> 6;
  int j  = threadIdx.x & 63;
  const float* mv = mvL + lp*256;
  const float* s  = sL  + lp*32;
  int gp = p0 + lp;
  int b = gp >> 11, q = gp & 2047;   // NQL = 2048
  for (int idx = j; idx < HN*DQK; idx += 64) {
    int h = idx / DQK, f = idx - h*DQK;
    float val = 0.f;
    if (f < 128) {
      int c = f >> 3;
      int a = c_inner[f & 7];
      int y = c_grade[a];
      int o = c*HN + h;
      for (int ci = 0; ci < 16; ci++) val += qw_mv[(o*16+ci)*9 + y] * mv[ci*16 + a];
      if (a == 0) {
        for (int i2 = 0; i2 < 32; i2++) val += s[i2] * qw_s2mv[o*32 + i2];
        val += qb_mv[o];
      }
    } else {
      int si = f - 128;
      int o = si*HN + h;    // FIXED: weight rows are indexed by full output index o,
      for (int ci = 0; ci < 16; ci++) val += mv[ci*16] * qw_mv2s[o*16 + ci];   // not si
      for (int i2 = 0; i2 < 32; i2++) val += s[i2] * qw_s2s[o*32 + i2];
      val += qb_s[o];
    }
    Qf[((size_t)(b*HN + h)*NQL + q)*DQK + f] = val;
  }
}

// ---------------- Flash attention ----------------
#define DOT4(ACC, U, V) ACC += U.x*V.x + U.y*V.y + U.z*V.z + U.w*V.w

__global__ __launch_bounds__(256, 2) void attn_kernel(
    const float* __restrict__ Kf, const float* __restrict__ Vf,
    const float* __restrict__ Qf, float* __restrict__ Hf)
{
  __shared__ alignas(16) float qfL[QT*QFP];
  __shared__ alignas(16) float kfL[KTL*KFP];
  __shared__ alignas(16) float pL[QT*PP];
  __shared__ float efL[QT];
  __shared__ float lL[QT];

  const int NT = NQL / QT;          // 64 q-tiles
  int bh    = blockIdx.x / NT;
  int qtile = blockIdx.x - bh*NT;
  int b = bh >> 3;
  int h = bh & 7;
  int t = threadIdx.x;

  const float* qbase = Qf + ((size_t)bh*NQL + (size_t)qtile*QT)*DQK;
  for (int i = t; i < QT*DQK; i += 256) {
    int r = i / DQK, f = i - r*DQK;
    qfL[r*QFP + f] = qbase[i];
  }

  int tq = t >> 4, tk = t & 15;     // 16 row-groups x 16 col-groups
  int r0 = tq*2;                    // each thread: rows r0,r0+1; cols tk+16j
  float m0 = -INFINITY, m1 = -INFINITY;
  float l0 = 0.f, l1 = 0.f;
  float acc0[QT], acc1[QT];
#pragma unroll
  for (int r = 0; r < QT; r++) { acc0[r] = 0.f; acc1[r] = 0.f; }

  const float scale = 0.07905694150420949f;   // 1/sqrt(160)
  const float* kbase = Kf + (size_t)b*NKVL*DQK;
  const float* vbase = Vf + (size_t)b*NKVL*DV;

  for (int kt0 = 0; kt0 < NKVL; kt0 += KTL) {
    for (int i = t; i < KTL*DQK; i += 256) {
      int r = i / DQK, f = i - r*DQK;
      kfL[r*KFP + f] = kbase[(size_t)kt0*DQK + i];
    }
    __syncthreads();

    const float4* qp0 = (const float4*)(qfL + r0*QFP);
    const float4* qp1 = (const float4*)(qfL + (r0+1)*QFP);
    const float4* kp0 = (const float4*)(kfL + tk*KFP);
    const float4* kp1 = (const float4*)(kfL + (tk+16)*KFP);
    const float4* kp2 = (const float4*)(kfL + (tk+32)*KFP);
    const float4* kp3 = (const float4*)(kfL + (tk+48)*KFP);

    float a00=0.f,a01=0.f,a02=0.f,a03=0.f;
    float a10=0.f,a11=0.f,a12=0.f,a13=0.f;
#pragma unroll 4
    for (int d = 0; d < DQK/4; d++) {
      float4 qa = qp0[d];
      float4 qb = qp1[d];
      float4 k0 = kp0[d];
      float4 k1 = kp1[d];
      float4 k2 = kp2[d];
      float4 k3 = kp3[d];
      DOT4(a00, qa, k0); DOT4(a01, qa, k1); DOT4(a02, qa, k2); DOT4(a03, qa, k3);
      DOT4(a10, qb, k0); DOT4(a11, qb, k1); DOT4(a12, qb, k2); DOT4(a13, qb, k3);
    }
    a00 *= scale; a01 *= scale; a02 *= scale; a03 *= scale;
    a10 *= scale; a11 *= scale; a12 *= scale; a13 *= scale;

    float rm0 = fmaxf(fmaxf(a00,a01), fmaxf(a02,a03));
    float rm1 = fmaxf(fmaxf(a10,a11), fmaxf(a12,a13));
#pragma unroll
    for (int off = 1; off < 16; off <<= 1) {
      rm0 = fmaxf(rm0, __shfl_xor(rm0, off));
      rm1 = fmaxf(rm1, __shfl_xor(rm1, off));
    }
    float nm0 = fmaxf(m0, rm0);
    float nm1 = fmaxf(m1, rm1);
    float ef0 = __expf(m0 - nm0);
    float ef1 = __expf(m1 - nm1);
    a00 = __expf(a00 - nm0); a01 = __expf(a01 - nm0);
    a02 = __expf(a02 - nm0); a03 = __expf(a03 - nm0);
    a10 = __expf(a10 - nm1); a11 = __expf(a11 - nm1);
    a12 = __expf(a12 - nm1); a13 = __expf(a13 - nm1);
    float rs0 = (a00+a01) + (a02+a03);
    float rs1 = (a10+a11) + (a12+a13);
#pragma unroll
    for (int off = 1; off < 16; off <<= 1) {
      rs0 += __shfl_xor(rs0, off);
      rs1 += __shfl_xor(rs1, off);
    }
    l0 = l0*ef0 + rs0;
    l1 = l1*ef1 + rs1;
    m0 = nm0; m1 = nm1;

    pL[r0*PP + tk     ] = a00;
    pL[r0*PP + tk + 16] = a01;
    pL[r0*PP + tk + 32] = a02;
    pL[r0*PP + tk + 48] = a03;
    pL[(r0+1)*PP + tk     ] = a10;
    pL[(r0+1)*PP + tk + 16] = a11;
    pL[(r0+1)*PP + tk + 32] = a12;
    pL[(r0+1)*PP + tk + 48] = a13;
    if (tk == 0) { efL[r0] = ef0; efL[r0+1] = ef1; lL[r0] = l0; lL[r0+1] = l1; }
    __syncthreads();

    // PV: thread t owns v-dim t (all 256), plus dim 256+t for t<32.
#pragma unroll
    for (int r = 0; r < QT; r++) { float e = efL[r]; acc0[r] *= e; acc1[r] *= e; }
    const float* vrow = vbase + (size_t)kt0*DV;
    for (int kk = 0; kk < KTL; kk += 4) {
      float v00 = vrow[(kk+0)*DV + t];
      float v01 = vrow[(kk+1)*DV + t];
      float v02 = vrow[(kk+2)*DV + t];
      float v03 = vrow[(kk+3)*DV + t];
      float v10 = 0.f, v11 = 0.f, v12 = 0.f, v13 = 0.f;
      if (t < 32) {
        v10 = vrow[(kk+0)*DV + 256 + t];
        v11 = vrow[(kk+1)*DV + 256 + t];
        v12 = vrow[(kk+2)*DV + 256 + t];
        v13 = vrow[(kk+3)*DV + 256 + t];
      }
#pragma unroll
      for (int r = 0; r < QT; r++) {
        float4 p4 = *(const float4*)(pL + r*PP + kk);   // broadcast read
        acc0[r] += p4.x*v00 + p4.y*v01 + p4.z*v02 + p4.w*v03;
        if (t < 32) acc1[r] += p4.x*v10 + p4.y*v11 + p4.z*v12 + p4.w*v13;
      }
    }
  }

  // epilogue: divide by l, write H features head-major per position
#pragma unroll
  for (int r = 0; r < QT; r++) {
    float inv = 1.0f / lL[r];
    size_t q = (size_t)qtile*QT + r;
    float* orow = Hf + (((size_t)b*NQL + q)*HN + h)*DV;
    orow[t] = acc0[r] * inv;
    if (t < 32) orow[256 + t] = acc1[r] * inv;
  }
}

// ---------------- Output projection ----------------
// Input channel for mv: ch = h*16 + c (head-major merge); scalars: j = h*32 + si.
__global__ __launch_bounds__(256) void proj_o_kernel(
    const float* __restrict__ Hf,
    const float* __restrict__ ow_mv, const float* __restrict__ ow_s2mv, const float* __restrict__ ob_mv,
    const float* __restrict__ ow_mv2s, const float* __restrict__ ow_s2s, const float* __restrict__ ob_s,
    float* __restrict__ outp)
{
  __shared__ float hL[HN*DV];
  size_t p = blockIdx.x;   // b*NQ + q
  for (int i = threadIdx.x; i < HN*DV; i += 256) hL[i] = Hf[p*(HN*DV) + i];
  __syncthreads();
  int t = threadIdx.x;
  float* out_s = outp + (size_t)NB*NQL*256;
  for (int f = t; f < 288; f += 256) {
    if (f < 256) {
      int o = f >> 4, a = f & 15;
      int y = c_grade[a];
      float val = 0.f;
      for (int ch = 0; ch < 128; ch++)
        val += ow_mv[(o*128+ch)*9 + y] * hL[(ch >> 4)*DV + (ch & 15)*16 + a];
      int sa = c_esrc[a];
      if (sa >= 0) {
        int ey = c_ey[a];
        for (int ch = 0; ch < 128; ch++)
          val += ow_mv[(o*128+ch)*9 + ey] * hL[(ch >> 4)*DV + (ch & 15)*16 + sa];
      }
      if (a == 0) {
        for (int jj = 0; jj < 256; jj++)
          val += hL[(jj >> 5)*DV + 256 + (jj & 31)] * ow_s2mv[o*256 + jj];
        val += ob_mv[o];
      }
      outp[p*256 + f] = val;
    } else {
      int si = f - 256;
      float val = ob_s[si];
      for (int ch = 0; ch < 128; ch++)
        val += hL[(ch >> 4)*DV + (ch & 15)*16] * ow_mv2s[si*128 + ch];
      for (int jj = 0; jj < 256; jj++)
        val += hL[(jj >> 5)*DV + 256 + (jj & 31)] * ow_s2s[si*256 + jj];
      out_s[p*32 + si] = val;
    }
  }
}

extern "C" void kernel_launch(void* const* d_in, const int* in_sizes, int n_in,
                              void* d_out, int out_size, void* d_ws, size_t ws_size,
                              hipStream_t stream)
{
  const float* mv_kv = (const float*)d_in[0];
  const float* mv_q  = (const float*)d_in[1];
  const float* s_kv  = (const float*)d_in[2];
  const float* s_q   = (const float*)d_in[3];

  float* ws = (float*)d_ws;
  float* Kf = ws;                                   //  5.2 MB
  float* Vf = Kf + (size_t)NB*NKVL*DQK;             //  9.4 MB
  float* Qf = Vf + (size_t)NB*NKVL*DV;              // 41.9 MB
  float* Hf = Qf + (size_t)NB*HN*NQL*DQK;           // 75.5 MB
  // total workspace: 132,120,576 bytes

  proj_kv_kernel<<<NB*NKVL/8, 256, 0, stream>>>(mv_kv, s_kv,
      (const float*)d_in[10], (const float*)d_in[11], (const float*)d_in[12],
      (const float*)d_in[13], (const float*)d_in[14], (const float*)d_in[15],
      (const float*)d_in[16], (const float*)d_in[17], (const float*)d_in[18],
      (const float*)d_in[19], (const float*)d_in[20], (const float*)d_in[21],
      Kf, Vf);
  proj_q_kernel<<<NB*NQL/4, 256, 0, stream>>>(mv_q, s_q,
      (const float*)d_in[4], (const float*)d_in[5], (const float*)d_in[6],
      (const float*)d_in[7], (const float*)d_in[8], (const float*)d_in[9],
      Qf);
  attn_kernel<<<NB*HN*(NQL/QT), 256, 0, stream>>>(Kf, Vf, Qf, Hf);
  proj_o_kernel<<<NB*NQL, 256, 0, stream>>>(Hf,
      (const float*)d_in[22], (const float*)d_in[23], (const float*)d_in[24],
      (const float*)d_in[25], (const float*)d_in[26], (const float*)d_in[27],
      (float*)d_out);
}

// Round 3
// 582.485 us; speedup vs baseline: 8.5045x; 8.5045x over previous
//
#include <hip/hip_runtime.h>
#include <hip/hip_bf16.h>
#include <math.h>

// Problem constants
#define NB   4
#define NQL  2048
#define NKVL 2048
#define HN   8
#define DQK  160    // qk feature dim
#define DV   288    // v feature dim
#define QT   64     // q rows per block (4 waves x 16)
#define KTL  64     // kv per tile
#define KLP  168    // K LDS row stride (bf16 elems) - uniform bank spread

#define SCALE 0.07905694150420949f   // 1/sqrt(160), folded into Q

typedef __attribute__((ext_vector_type(8))) short short8;
typedef __attribute__((ext_vector_type(4))) float f32x4;
typedef __attribute__((ext_vector_type(4))) int int4v;

__constant__ int c_grade[16] = {0,1,1,1,1,2,2,2,2,2,2,3,3,3,3,4};
__constant__ int c_inner[8]  = {0,2,3,4,8,9,10,14};
__constant__ int c_esrc[16]  = {-1,0,-1,-1,-1,2,3,4,-1,-1,-1,8,9,10,-1,14};
__constant__ int c_ey[16]    = {0,5,0,0,0,6,6,6,0,0,0,7,7,7,0,8};

__device__ __forceinline__ ushort f2bf(float v) {
  __hip_bfloat16 h = __float2bfloat16(v);
  union { __hip_bfloat16 b; ushort u; } cv; cv.b = h; return cv.u;
}

// ---------------- K/V projection ----------------
// Kf bf16 [b][kv][160]; VfT bf16 [b][288][kv]
__global__ __launch_bounds__(256) void proj_kv_kernel(
    const float* __restrict__ mv_kv, const float* __restrict__ s_kv,
    const float* __restrict__ kw_mv, const float* __restrict__ kw_s2mv, const float* __restrict__ kb_mv,
    const float* __restrict__ kw_mv2s, const float* __restrict__ kw_s2s, const float* __restrict__ kb_s,
    const float* __restrict__ vw_mv, const float* __restrict__ vw_s2mv, const float* __restrict__ vb_mv,
    const float* __restrict__ vw_mv2s, const float* __restrict__ vw_s2s, const float* __restrict__ vb_s,
    ushort* __restrict__ Kf, ushort* __restrict__ VfT)
{
  __shared__ float mvL[8*256];
  __shared__ float sL[8*32];
  int p0 = blockIdx.x * 8;
  for (int i = threadIdx.x; i < 8*256; i += 256) mvL[i] = mv_kv[(size_t)p0*256 + i];
  for (int i = threadIdx.x; i < 8*32;  i += 256) sL[i]  = s_kv[(size_t)p0*32 + i];
  __syncthreads();
  int lp = threadIdx.x >> 5;
  int j  = threadIdx.x & 31;
  const float* mv = mvL + lp*256;
  const float* s  = sL  + lp*32;
  size_t gp = (size_t)p0 + lp;
  int b = (int)(gp >> 11), kv = (int)(gp & 2047);
  for (int f = j; f < DQK + DV; f += 32) {
    float val = 0.f;
    if (f < DQK) {
      if (f < 128) {
        int c = f >> 3;
        int a = c_inner[f & 7];
        int y = c_grade[a];
        for (int ci = 0; ci < 16; ci++) val += kw_mv[(c*16+ci)*9 + y] * mv[ci*16 + a];
        if (a == 0) {
          for (int i2 = 0; i2 < 32; i2++) val += s[i2] * kw_s2mv[c*32 + i2];
          val += kb_mv[c];
        }
      } else {
        int si = f - 128;
        for (int ci = 0; ci < 16; ci++) val += mv[ci*16] * kw_mv2s[si*16 + ci];
        for (int i2 = 0; i2 < 32; i2++) val += s[i2] * kw_s2s[si*32 + i2];
        val += kb_s[si];
      }
      Kf[gp*DQK + f] = f2bf(val);
    } else {
      int g = f - DQK;
      if (g < 256) {
        int c = g >> 4, a = g & 15;
        int y = c_grade[a];
        for (int ci = 0; ci < 16; ci++) val += vw_mv[(c*16+ci)*9 + y] * mv[ci*16 + a];
        int sa = c_esrc[a];
        if (sa >= 0) {
          int ey = c_ey[a];
          for (int ci = 0; ci < 16; ci++) val += vw_mv[(c*16+ci)*9 + ey] * mv[ci*16 + sa];
        }
        if (a == 0) {
          for (int i2 = 0; i2 < 32; i2++) val += s[i2] * vw_s2mv[c*32 + i2];
          val += vb_mv[c];
        }
      } else {
        int si = g - 256;
        for (int ci = 0; ci < 16; ci++) val += mv[ci*16] * vw_mv2s[si*16 + ci];
        for (int i2 = 0; i2 < 32; i2++) val += s[i2] * vw_s2s[si*32 + i2];
        val += vb_s[si];
      }
      VfT[((size_t)b*DV + g)*NKVL + kv] = f2bf(val);
    }
  }
}

// ---------------- Q projection ----------------
// Qf bf16 [b*H+h][q][160], pre-scaled by 1/sqrt(160)
__global__ __launch_bounds__(256) void proj_q_kernel(
    const float* __restrict__ mv_q, const float* __restrict__ s_q,
    const float* __restrict__ qw_mv, const float* __restrict__ qw_s2mv, const float* __restrict__ qb_mv,
    const float* __restrict__ qw_mv2s, const float* __restrict__ qw_s2s, const float* __restrict__ qb_s,
    ushort* __restrict__ Qf)
{
  __shared__ float mvL[4*256];
  __shared__ float sL[4*32];
  int p0 = blockIdx.x * 4;
  for (int i = threadIdx.x; i < 4*256; i += 256) mvL[i] = mv_q[(size_t)p0*256 + i];
  if (threadIdx.x < 4*32) sL[threadIdx.x] = s_q[(size_t)p0*32 + threadIdx.x];
  __syncthreads();
  int lp = threadIdx.x >> 6;
  int j  = threadIdx.x & 63;
  const float* mv = mvL + lp*256;
  const float* s  = sL  + lp*32;
  int gp = p0 + lp;
  int b = gp >> 11, q = gp & 2047;
  for (int idx = j; idx < HN*DQK; idx += 64) {
    int h = idx / DQK, f = idx - h*DQK;
    float val = 0.f;
    if (f < 128) {
      int c = f >> 3;
      int a = c_inner[f & 7];
      int y = c_grade[a];
      int o = c*HN + h;
      for (int ci = 0; ci < 16; ci++) val += qw_mv[(o*16+ci)*9 + y] * mv[ci*16 + a];
      if (a == 0) {
        for (int i2 = 0; i2 < 32; i2++) val += s[i2] * qw_s2mv[o*32 + i2];
        val += qb_mv[o];
      }
    } else {
      int si = f - 128;
      int o = si*HN + h;
      for (int ci = 0; ci < 16; ci++) val += mv[ci*16] * qw_mv2s[o*16 + ci];
      for (int i2 = 0; i2 < 32; i2++) val += s[i2] * qw_s2s[o*32 + i2];
      val += qb_s[o];
    }
    Qf[((size_t)(b*HN + h)*NQL + q)*DQK + f] = f2bf(val * SCALE);
  }
}

// ---------------- MFMA flash attention ----------------
// S^T = K·Q^T per 16q-wave; softmax in-register (per-lane col = q);
// O^T = V^T·P^T with P^T fragments built via cvt_pk + shfl.
__global__ __launch_bounds__(256, 2) void attn_kernel(
    const ushort* __restrict__ Kf,   // [b][2048][160]
    const ushort* __restrict__ VfT,  // [b][288][2048]
    const ushort* __restrict__ Qf,   // [bh][2048][160] (scaled)
    float* __restrict__ Hf)          // [b][q][h][288]
{
  __shared__ ushort kL[KTL*KLP];     // 21504 B
  __shared__ ushort vtL[DV*KTL];     // 36864 B, XOR-swizzled

  const int NT = NQL/QT;             // 32
  int bh = blockIdx.x / NT;
  int qt = blockIdx.x - bh*NT;
  int b = bh >> 3, h = bh & 7;
  int t = threadIdx.x, w = t >> 6, l = t & 63;
  int ql = l & 15, g = l >> 4;

  // Q fragments, held in registers for whole kernel.
  // B-frag: lane holds Q[q=ql][d=(g*8 .. +7) + 32*ks]
  const ushort* qrow = Qf + ((size_t)bh*NQL + (size_t)qt*QT + w*16 + ql)*DQK + g*8;
  short8 qf[5];
#pragma unroll
  for (int ks = 0; ks < 5; ks++)
    qf[ks] = *(const short8*)(qrow + ks*32);

  f32x4 oA[18];
#pragma unroll
  for (int i = 0; i < 18; i++) oA[i] = (f32x4)(0.f);
  float m = -INFINITY, lsum = 0.f;

  const ushort* kb = Kf  + (size_t)b*NKVL*DQK;
  const ushort* vb = VfT + (size_t)b*DV*NKVL;

  for (int kt0 = 0; kt0 < NKVL; kt0 += KTL) {
    // stage K tile: 64 rows x 160 elems = 1280 16B-chunks, 5 iters
#pragma unroll
    for (int it = 0; it < 5; it++) {
      int i = t + it*256;
      int r = i / 20, c = i - r*20;
      int4v val = *(const int4v*)(kb + (size_t)(kt0 + r)*DQK + c*8);
      *(int4v*)(kL + r*KLP + c*8) = val;
    }
    // stage V^T tile: 288 rows x 64 elems = 2304 chunks, 9 iters; XOR swizzle
#pragma unroll
    for (int it = 0; it < 9; it++) {
      int i = t + it*256;
      int d = i >> 3, c = i & 7;
      int4v val = *(const int4v*)(vb + (size_t)d*NKVL + kt0 + c*8);
      int col = (c*8) ^ ((d & 7) << 3);
      *(int4v*)(vtL + d*64 + col) = val;
    }
    __syncthreads();

    // scores S^T: 4 tiles (16kv x 16q); lane: kv=(g*4+r)+16*kvb, q=ql
    f32x4 sA[4];
#pragma unroll
    for (int kvb = 0; kvb < 4; kvb++) {
      sA[kvb] = (f32x4)(0.f);
      const ushort* krow = kL + (ql + 16*kvb)*KLP + g*8;
#pragma unroll
      for (int ks = 0; ks < 5; ks++) {
        short8 kf = *(const short8*)(krow + ks*32);
        sA[kvb] = __builtin_amdgcn_mfma_f32_16x16x32_bf16(kf, qf[ks], sA[kvb], 0, 0, 0);
      }
    }

    // online softmax (scale pre-folded into Q)
    float tm = sA[0][0];
#pragma unroll
    for (int kvb = 0; kvb < 4; kvb++)
#pragma unroll
      for (int r = 0; r < 4; r++) tm = fmaxf(tm, sA[kvb][r]);
    tm = fmaxf(tm, __shfl_xor(tm, 16));
    tm = fmaxf(tm, __shfl_xor(tm, 32));
    float nm = fmaxf(m, tm);
    float ef = __expf(m - nm);
    float rs = 0.f;
#pragma unroll
    for (int kvb = 0; kvb < 4; kvb++)
#pragma unroll
      for (int r = 0; r < 4; r++) {
        float p = __expf(sA[kvb][r] - nm);
        sA[kvb][r] = p;
        rs += p;
      }
    rs += __shfl_xor(rs, 16);
    rs += __shfl_xor(rs, 32);
    lsum = lsum * ef + rs;
    m = nm;
#pragma unroll
    for (int i = 0; i < 18; i++) {
      oA[i][0] *= ef; oA[i][1] *= ef; oA[i][2] *= ef; oA[i][3] *= ef;
    }

    // pack P (f32) -> bf16 pairs: pk[kvb][p] = {P(kv=16kvb+4g+2p), P(+1)}
    unsigned int pk[4][2];
#pragma unroll
    for (int b2 = 0; b2 < 4; b2++)
#pragma unroll
      for (int p2 = 0; p2 < 2; p2++) {
        float lo = sA[b2][2*p2], hi = sA[b2][2*p2+1];
        unsigned int r_;
        asm("v_cvt_pk_bf16_f32 %0, %1, %2" : "=v"(r_) : "v"(lo), "v"(hi));
        pk[b2][p2] = r_;
      }

    // Build P^T B-frags via shuffle within 4-lane q-groups:
    // lane (ql,g) needs pk[2s+(g>>1)][*] from lanes g'=2(g&1), 2(g&1)+1
    int src0 = ql + ((l >> 4) & 1) * 32;
    int src1 = src0 + 16;
    bool hi_half = (l & 32) != 0;
#pragma unroll
    for (int s = 0; s < 2; s++) {
      unsigned int a0 = __shfl((int)pk[2*s][0], src0);
      unsigned int a1 = __shfl((int)pk[2*s][1], src0);
      unsigned int a2 = __shfl((int)pk[2*s][0], src1);
      unsigned int a3 = __shfl((int)pk[2*s][1], src1);
      unsigned int c0 = __shfl((int)pk[2*s+1][0], src0);
      unsigned int c1 = __shfl((int)pk[2*s+1][1], src0);
      unsigned int c2 = __shfl((int)pk[2*s+1][0], src1);
      unsigned int c3 = __shfl((int)pk[2*s+1][1], src1);
      union { unsigned int u[4]; short8 s8; } pf;
      pf.u[0] = hi_half ? c0 : a0;
      pf.u[1] = hi_half ? c1 : a1;
      pf.u[2] = hi_half ? c2 : a2;
      pf.u[3] = hi_half ? c3 : a3;
      // PV: oA[db] += V^T-frag x P^T-frag
#pragma unroll
      for (int db = 0; db < 18; db++) {
        int d = ql + 16*db;
        int col = (32*s + 8*g) ^ ((d & 7) << 3);
        short8 vf = *(const short8*)(vtL + d*64 + col);
        oA[db] = __builtin_amdgcn_mfma_f32_16x16x32_bf16(vf, pf.s8, oA[db], 0, 0, 0);
      }
    }
    __syncthreads();
  }

  // epilogue: O^T lane (d=g*4+r+16db, q=ql); 4 consecutive d -> float4 store
  float inv = 1.0f / lsum;
  int q = qt*QT + w*16 + ql;
  float* orow = Hf + (((size_t)b*NQL + q)*HN + h)*DV;
#pragma unroll
  for (int db = 0; db < 18; db++) {
    float4 st = make_float4(oA[db][0]*inv, oA[db][1]*inv, oA[db][2]*inv, oA[db][3]*inv);
    *(float4*)(orow + 16*db + 4*g) = st;
  }
}

// ---------------- Output projection ----------------
__global__ __launch_bounds__(256) void proj_o_kernel(
    const float* __restrict__ Hf,
    const float* __restrict__ ow_mv, const float* __restrict__ ow_s2mv, const float* __restrict__ ob_mv,
    const float* __restrict__ ow_mv2s, const float* __restrict__ ow_s2s, const float* __restrict__ ob_s,
    float* __restrict__ outp)
{
  __shared__ float hL[HN*DV];
  size_t p = blockIdx.x;
  for (int i = threadIdx.x; i < HN*DV; i += 256) hL[i] = Hf[p*(HN*DV) + i];
  __syncthreads();
  int t = threadIdx.x;
  float* out_s = outp + (size_t)NB*NQL*256;
  for (int f = t; f < 288; f += 256) {
    if (f < 256) {
      int o = f >> 4, a = f & 15;
      int y = c_grade[a];
      float val = 0.f;
      for (int ch = 0; ch < 128; ch++)
        val += ow_mv[(o*128+ch)*9 + y] * hL[(ch >> 4)*DV + (ch & 15)*16 + a];
      int sa = c_esrc[a];
      if (sa >= 0) {
        int ey = c_ey[a];
        for (int ch = 0; ch < 128; ch++)
          val += ow_mv[(o*128+ch)*9 + ey] * hL[(ch >> 4)*DV + (ch & 15)*16 + sa];
      }
      if (a == 0) {
        for (int jj = 0; jj < 256; jj++)
          val += hL[(jj >> 5)*DV + 256 + (jj & 31)] * ow_s2mv[o*256 + jj];
        val += ob_mv[o];
      }
      outp[p*256 + f] = val;
    } else {
      int si = f - 256;
      float val = ob_s[si];
      for (int ch = 0; ch < 128; ch++)
        val += hL[(ch >> 4)*DV + (ch & 15)*16] * ow_mv2s[si*128 + ch];
      for (int jj = 0; jj < 256; jj++)
        val += hL[(jj >> 5)*DV + 256 + (jj & 31)] * ow_s2s[si*256 + jj];
      out_s[p*32 + si] = val;
    }
  }
}

extern "C" void kernel_launch(void* const* d_in, const int* in_sizes, int n_in,
                              void* d_out, int out_size, void* d_ws, size_t ws_size,
                              hipStream_t stream)
{
  const float* mv_kv = (const float*)d_in[0];
  const float* mv_q  = (const float*)d_in[1];
  const float* s_kv  = (const float*)d_in[2];
  const float* s_q   = (const float*)d_in[3];

  ushort* Kf  = (ushort*)d_ws;                          // 4*2048*160   bf16
  ushort* VfT = Kf  + (size_t)NB*NKVL*DQK;              // 4*288*2048   bf16
  ushort* Qf  = VfT + (size_t)NB*DV*NKVL;               // 4*8*2048*160 bf16
  float*  Hf  = (float*)(Qf + (size_t)NB*HN*NQL*DQK);   // 4*2048*8*288 f32
  // total ~104 MB

  proj_kv_kernel<<<NB*NKVL/8, 256, 0, stream>>>(mv_kv, s_kv,
      (const float*)d_in[10], (const float*)d_in[11], (const float*)d_in[12],
      (const float*)d_in[13], (const float*)d_in[14], (const float*)d_in[15],
      (const float*)d_in[16], (const float*)d_in[17], (const float*)d_in[18],
      (const float*)d_in[19], (const float*)d_in[20], (const float*)d_in[21],
      Kf, VfT);
  proj_q_kernel<<<NB*NQL/4, 256, 0, stream>>>(mv_q, s_q,
      (const float*)d_in[4], (const float*)d_in[5], (const float*)d_in[6],
      (const float*)d_in[7], (const float*)d_in[8], (const float*)d_in[9],
      Qf);
  attn_kernel<<<NB*HN*(NQL/QT), 256, 0, stream>>>(Kf, VfT, Qf, Hf);
  proj_o_kernel<<<NB*NQL, 256, 0, stream>>>(Hf,
      (const float*)d_in[22], (const float*)d_in[23], (const float*)d_in[24],
      (const float*)d_in[25], (const float*)d_in[26], (const float*)d_in[27],
      (float*)d_out);
}

// Round 5
// 509.899 us; speedup vs baseline: 9.7151x; 1.1424x over previous
//
#include <hip/hip_runtime.h>
#include <hip/hip_bf16.h>
#include <math.h>

// Problem constants
#define NB   4
#define NQL  2048
#define NKVL 2048
#define HN   8
#define DQK  160    // qk feature dim
#define DV   288    // v feature dim
#define QT   64     // q rows per block (4 waves x 16)
#define KTL  64     // kv per tile
#define KLP  168    // K LDS row stride (bf16 elems)

#define SCALE 0.07905694150420949f   // 1/sqrt(160), folded into Q

typedef __attribute__((ext_vector_type(8))) short short8;
typedef __attribute__((ext_vector_type(4))) float f32x4;
typedef __attribute__((ext_vector_type(4))) int int4v;

__constant__ int c_grade[16] = {0,1,1,1,1,2,2,2,2,2,2,3,3,3,3,4};
__constant__ int c_inner[8]  = {0,2,3,4,8,9,10,14};
__constant__ int c_esrc[16]  = {-1,0,-1,-1,-1,2,3,4,-1,-1,-1,8,9,10,-1,14};
__constant__ int c_ey[16]    = {0,5,0,0,0,6,6,6,0,0,0,7,7,7,0,8};

__device__ __forceinline__ ushort f2bf(float v) {
  __hip_bfloat16 h = __float2bfloat16(v);
  union { __hip_bfloat16 b; ushort u; } cv; cv.b = h; return cv.u;
}

// ---------------- K/V projection (weight-stationary, 32 pos/block) ----------------
#define KWMV   0
#define KS2MV  2304
#define KMV2S  2816
#define KS2S   3328
#define KBMV   4352
#define KBS    4368
#define VWMV   4400
#define VS2MV  6704
#define VMV2S  7216
#define VS2S   7728
#define VBMV   8752
#define VBS    8768
#define WLSZ   8800
#define XSTR   289   // pos stride in xL (289 % 32 == 1 -> conflict-free)
#define OSTR   456   // pos stride in oL (ushort)

__device__ __forceinline__ void kv_accum(const float* wL, const float* xL,
                                         int f, float acc[32]) {
  if (f < 160) {
    if (f < 128) {                      // K mv-feature
      int c = f >> 3, a = c_inner[f & 7], y = c_grade[a];
      float bias = (a == 0) ? wL[KBMV + c] : 0.f;
#pragma unroll
      for (int p = 0; p < 32; p++) acc[p] = bias;
      for (int ci = 0; ci < 16; ci++) {
        float w = wL[KWMV + (c*16 + ci)*9 + y];
#pragma unroll
        for (int p = 0; p < 32; p++) acc[p] += w * xL[p*XSTR + ci*16 + a];
      }
      if (a == 0) {
        for (int i2 = 0; i2 < 32; i2++) {
          float w = wL[KS2MV + c*32 + i2];
#pragma unroll
          for (int p = 0; p < 32; p++) acc[p] += w * xL[p*XSTR + 256 + i2];
        }
      }
    } else {                            // K scalar
      int si = f - 128;
      float bias = wL[KBS + si];
#pragma unroll
      for (int p = 0; p < 32; p++) acc[p] = bias;
      for (int ci = 0; ci < 16; ci++) {
        float w = wL[KMV2S + si*16 + ci];
#pragma unroll
        for (int p = 0; p < 32; p++) acc[p] += w * xL[p*XSTR + ci*16];
      }
      for (int i2 = 0; i2 < 32; i2++) {
        float w = wL[KS2S + si*32 + i2];
#pragma unroll
        for (int p = 0; p < 32; p++) acc[p] += w * xL[p*XSTR + 256 + i2];
      }
    }
  } else {
    int g = f - 160;
    if (g < 256) {                      // V mv-feature
      int c = g >> 4, a = g & 15, y = c_grade[a];
      float bias = (a == 0) ? wL[VBMV + c] : 0.f;
#pragma unroll
      for (int p = 0; p < 32; p++) acc[p] = bias;
      for (int ci = 0; ci < 16; ci++) {
        float w = wL[VWMV + (c*16 + ci)*9 + y];
#pragma unroll
        for (int p = 0; p < 32; p++) acc[p] += w * xL[p*XSTR + ci*16 + a];
      }
      int sa = c_esrc[a];
      if (sa >= 0) {
        int ey = c_ey[a];
        for (int ci = 0; ci < 16; ci++) {
          float w = wL[VWMV + (c*16 + ci)*9 + ey];
#pragma unroll
          for (int p = 0; p < 32; p++) acc[p] += w * xL[p*XSTR + ci*16 + sa];
        }
      }
      if (a == 0) {
        for (int i2 = 0; i2 < 32; i2++) {
          float w = wL[VS2MV + c*32 + i2];
#pragma unroll
          for (int p = 0; p < 32; p++) acc[p] += w * xL[p*XSTR + 256 + i2];
        }
      }
    } else {                            // V scalar
      int si = g - 256;
      float bias = wL[VBS + si];
#pragma unroll
      for (int p = 0; p < 32; p++) acc[p] = bias;
      for (int ci = 0; ci < 16; ci++) {
        float w = wL[VMV2S + si*16 + ci];
#pragma unroll
        for (int p = 0; p < 32; p++) acc[p] += w * xL[p*XSTR + ci*16];
      }
      for (int i2 = 0; i2 < 32; i2++) {
        float w = wL[VS2S + si*32 + i2];
#pragma unroll
        for (int p = 0; p < 32; p++) acc[p] += w * xL[p*XSTR + 256 + i2];
      }
    }
  }
}

__global__ __launch_bounds__(256) void proj_kv_kernel(
    const float* __restrict__ mv_kv, const float* __restrict__ s_kv,
    const float* __restrict__ kw_mv, const float* __restrict__ kw_s2mv, const float* __restrict__ kb_mv,
    const float* __restrict__ kw_mv2s, const float* __restrict__ kw_s2s, const float* __restrict__ kb_s,
    const float* __restrict__ vw_mv, const float* __restrict__ vw_s2mv, const float* __restrict__ vb_mv,
    const float* __restrict__ vw_mv2s, const float* __restrict__ vw_s2s, const float* __restrict__ vb_s,
    ushort* __restrict__ Kf, ushort* __restrict__ VfT)
{
  __shared__ float wL[WLSZ];
  __shared__ float xL[32*XSTR];
  int t = threadIdx.x;
  for (int i = t; i < 2304; i += 256) wL[KWMV + i] = kw_mv[i];
  for (int i = t; i < 512;  i += 256) wL[KS2MV + i] = kw_s2mv[i];
  for (int i = t; i < 512;  i += 256) wL[KMV2S + i] = kw_mv2s[i];
  for (int i = t; i < 1024; i += 256) wL[KS2S + i] = kw_s2s[i];
  if (t < 16) wL[KBMV + t] = kb_mv[t];
  if (t < 32) wL[KBS + t] = kb_s[t];
  for (int i = t; i < 2304; i += 256) wL[VWMV + i] = vw_mv[i];
  for (int i = t; i < 512;  i += 256) wL[VS2MV + i] = vw_s2mv[i];
  for (int i = t; i < 512;  i += 256) wL[VMV2S + i] = vw_mv2s[i];
  for (int i = t; i < 1024; i += 256) wL[VS2S + i] = vw_s2s[i];
  if (t < 16) wL[VBMV + t] = vb_mv[t];
  if (t < 32) wL[VBS + t] = vb_s[t];

  int p0 = blockIdx.x * 32;
  for (int i = t; i < 32*256; i += 256) {
    int p = i >> 8, c = i & 255;
    xL[p*XSTR + c] = mv_kv[(size_t)(p0 + p)*256 + c];
  }
  for (int i = t; i < 32*32; i += 256) {
    int p = i >> 5, c = i & 31;
    xL[p*XSTR + 256 + c] = s_kv[(size_t)(p0 + p)*32 + c];
  }
  __syncthreads();

  float acc0[32], acc1[32];
  kv_accum(wL, xL, t, acc0);
  if (t < 192) kv_accum(wL, xL, 256 + t, acc1);
  __syncthreads();

  // stage outputs bf16 in LDS (alias xL), then coalesced global writes
  ushort* oL = (ushort*)xL;
#pragma unroll
  for (int p = 0; p < 32; p++) oL[p*OSTR + t] = f2bf(acc0[p]);
  if (t < 192) {
#pragma unroll
    for (int p = 0; p < 32; p++) oL[p*OSTR + 256 + t] = f2bf(acc1[p]);
  }
  __syncthreads();

  int b = p0 >> 11, kv0 = p0 & 2047;
  // K: rows [p][160] -> packed uint stores
  for (int it = 0; it < 10; it++) {
    int j = t + it*256;                 // 0..2559
    int p = j / 80, fp = j - p*80;
    uint u = (uint)oL[p*OSTR + 2*fp] | ((uint)oL[p*OSTR + 2*fp + 1] << 16);
    *(uint*)(Kf + (size_t)(p0 + p)*DQK + 2*fp) = u;
  }
  // V^T: [g][kv] -> pack 2 consecutive kv
  for (int it = 0; it < 18; it++) {
    int j = t + it*256;                 // 0..4607
    int g = j >> 4, pp = j & 15;
    uint u = (uint)oL[(2*pp)*OSTR + 160 + g] | ((uint)oL[(2*pp+1)*OSTR + 160 + g] << 16);
    *(uint*)(VfT + ((size_t)b*DV + g)*NKVL + kv0 + 2*pp) = u;
  }
}

// ---------------- Q projection (shared-x across heads, 16 pos/block) ----------------
__global__ __launch_bounds__(320) void proj_q_kernel(
    const float* __restrict__ mv_q, const float* __restrict__ s_q,
    const float* __restrict__ qw_mv, const float* __restrict__ qw_s2mv, const float* __restrict__ qb_mv,
    const float* __restrict__ qw_mv2s, const float* __restrict__ qw_s2s, const float* __restrict__ qb_s,
    ushort* __restrict__ Qf)
{
  __shared__ float xL[16*XSTR];
  int t = threadIdx.x;
  int p0 = blockIdx.x * 16;
  for (int i = t; i < 16*256; i += 320) {
    int p = i >> 8, c = i & 255;
    xL[p*XSTR + c] = mv_q[(size_t)(p0 + p)*256 + c];
  }
  for (int i = t; i < 16*32; i += 320) {
    int p = i >> 5, c = i & 31;
    xL[p*XSTR + 256 + c] = s_q[(size_t)(p0 + p)*32 + c];
  }
  __syncthreads();

  int f0 = t % 160;
  int h0 = t / 160;        // 0 or 1; heads h0, h0+2, h0+4, h0+6
  float acc[4][16];

  if (f0 < 128) {
    int c = f0 >> 3, a = c_inner[f0 & 7], y = c_grade[a];
    int o0 = c*HN + h0, o1 = o0 + 2, o2 = o0 + 4, o3 = o0 + 6;
#pragma unroll
    for (int p = 0; p < 16; p++) {
      float bv0 = (a == 0) ? qb_mv[o0] : 0.f;
      float bv1 = (a == 0) ? qb_mv[o1] : 0.f;
      float bv2 = (a == 0) ? qb_mv[o2] : 0.f;
      float bv3 = (a == 0) ? qb_mv[o3] : 0.f;
      acc[0][p] = bv0; acc[1][p] = bv1; acc[2][p] = bv2; acc[3][p] = bv3;
    }
    for (int ci = 0; ci < 16; ci++) {
      float w0 = qw_mv[(o0*16 + ci)*9 + y];
      float w1 = qw_mv[(o1*16 + ci)*9 + y];
      float w2 = qw_mv[(o2*16 + ci)*9 + y];
      float w3 = qw_mv[(o3*16 + ci)*9 + y];
#pragma unroll
      for (int p = 0; p < 16; p++) {
        float xv = xL[p*XSTR + ci*16 + a];
        acc[0][p] += w0*xv; acc[1][p] += w1*xv;
        acc[2][p] += w2*xv; acc[3][p] += w3*xv;
      }
    }
    if (a == 0) {
      for (int i2 = 0; i2 < 32; i2++) {
        float w0 = qw_s2mv[o0*32 + i2];
        float w1 = qw_s2mv[o1*32 + i2];
        float w2 = qw_s2mv[o2*32 + i2];
        float w3 = qw_s2mv[o3*32 + i2];
#pragma unroll
        for (int p = 0; p < 16; p++) {
          float xv = xL[p*XSTR + 256 + i2];
          acc[0][p] += w0*xv; acc[1][p] += w1*xv;
          acc[2][p] += w2*xv; acc[3][p] += w3*xv;
        }
      }
    }
  } else {
    int si = f0 - 128;
    int o0 = si*HN + h0, o1 = o0 + 2, o2 = o0 + 4, o3 = o0 + 6;
#pragma unroll
    for (int p = 0; p < 16; p++) {
      acc[0][p] = qb_s[o0]; acc[1][p] = qb_s[o1];
      acc[2][p] = qb_s[o2]; acc[3][p] = qb_s[o3];
    }
    for (int ci = 0; ci < 16; ci++) {
      float w0 = qw_mv2s[o0*16 + ci];
      float w1 = qw_mv2s[o1*16 + ci];
      float w2 = qw_mv2s[o2*16 + ci];
      float w3 = qw_mv2s[o3*16 + ci];
#pragma unroll
      for (int p = 0; p < 16; p++) {
        float xv = xL[p*XSTR + ci*16];
        acc[0][p] += w0*xv; acc[1][p] += w1*xv;
        acc[2][p] += w2*xv; acc[3][p] += w3*xv;
      }
    }
    for (int i2 = 0; i2 < 32; i2++) {
      float w0 = qw_s2s[o0*32 + i2];
      float w1 = qw_s2s[o1*32 + i2];
      float w2 = qw_s2s[o2*32 + i2];
      float w3 = qw_s2s[o3*32 + i2];
#pragma unroll
      for (int p = 0; p < 16; p++) {
        float xv = xL[p*XSTR + 256 + i2];
        acc[0][p] += w0*xv; acc[1][p] += w1*xv;
        acc[2][p] += w2*xv; acc[3][p] += w3*xv;
      }
    }
  }

  int b = p0 >> 11, q0 = p0 & 2047;
#pragma unroll
  for (int k = 0; k < 4; k++) {
    int h = h0 + 2*k;
    ushort* qdst = Qf + ((size_t)(b*HN + h)*NQL + q0)*DQK + f0;
#pragma unroll
    for (int p = 0; p < 16; p++)
      qdst[p*DQK] = f2bf(acc[k][p] * SCALE);
  }
}

// ---------------- MFMA flash attention (unchanged) ----------------
__global__ __launch_bounds__(256, 2) void attn_kernel(
    const ushort* __restrict__ Kf,   // [b][2048][160]
    const ushort* __restrict__ VfT,  // [b][288][2048]
    const ushort* __restrict__ Qf,   // [bh][2048][160] (scaled)
    float* __restrict__ Hf)          // [b][q][h][288]
{
  __shared__ ushort kL[KTL*KLP];
  __shared__ ushort vtL[DV*KTL];

  const int NT = NQL/QT;
  int bh = blockIdx.x / NT;
  int qt = blockIdx.x - bh*NT;
  int b = bh >> 3, h = bh & 7;
  int t = threadIdx.x, w = t >> 6, l = t & 63;
  int ql = l & 15, g = l >> 4;

  const ushort* qrow = Qf + ((size_t)bh*NQL + (size_t)qt*QT + w*16 + ql)*DQK + g*8;
  short8 qf[5];
#pragma unroll
  for (int ks = 0; ks < 5; ks++)
    qf[ks] = *(const short8*)(qrow + ks*32);

  f32x4 oA[18];
#pragma unroll
  for (int i = 0; i < 18; i++) oA[i] = (f32x4)(0.f);
  float m = -INFINITY, lsum = 0.f;

  const ushort* kb = Kf  + (size_t)b*NKVL*DQK;
  const ushort* vb = VfT + (size_t)b*DV*NKVL;

  for (int kt0 = 0; kt0 < NKVL; kt0 += KTL) {
#pragma unroll
    for (int it = 0; it < 5; it++) {
      int i = t + it*256;
      int r = i / 20, c = i - r*20;
      int4v val = *(const int4v*)(kb + (size_t)(kt0 + r)*DQK + c*8);
      *(int4v*)(kL + r*KLP + c*8) = val;
    }
#pragma unroll
    for (int it = 0; it < 9; it++) {
      int i = t + it*256;
      int d = i >> 3, c = i & 7;
      int4v val = *(const int4v*)(vb + (size_t)d*NKVL + kt0 + c*8);
      int col = (c*8) ^ ((d & 7) << 3);
      *(int4v*)(vtL + d*64 + col) = val;
    }
    __syncthreads();

    f32x4 sA[4];
#pragma unroll
    for (int kvb = 0; kvb < 4; kvb++) {
      sA[kvb] = (f32x4)(0.f);
      const ushort* krow = kL + (ql + 16*kvb)*KLP + g*8;
#pragma unroll
      for (int ks = 0; ks < 5; ks++) {
        short8 kf = *(const short8*)(krow + ks*32);
        sA[kvb] = __builtin_amdgcn_mfma_f32_16x16x32_bf16(kf, qf[ks], sA[kvb], 0, 0, 0);
      }
    }

    float tm = sA[0][0];
#pragma unroll
    for (int kvb = 0; kvb < 4; kvb++)
#pragma unroll
      for (int r = 0; r < 4; r++) tm = fmaxf(tm, sA[kvb][r]);
    tm = fmaxf(tm, __shfl_xor(tm, 16));
    tm = fmaxf(tm, __shfl_xor(tm, 32));
    float nm = fmaxf(m, tm);
    float ef = __expf(m - nm);
    float rs = 0.f;
#pragma unroll
    for (int kvb = 0; kvb < 4; kvb++)
#pragma unroll
      for (int r = 0; r < 4; r++) {
        float p = __expf(sA[kvb][r] - nm);
        sA[kvb][r] = p;
        rs += p;
      }
    rs += __shfl_xor(rs, 16);
    rs += __shfl_xor(rs, 32);
    lsum = lsum * ef + rs;
    m = nm;
#pragma unroll
    for (int i = 0; i < 18; i++) {
      oA[i][0] *= ef; oA[i][1] *= ef; oA[i][2] *= ef; oA[i][3] *= ef;
    }

    unsigned int pk[4][2];
#pragma unroll
    for (int b2 = 0; b2 < 4; b2++)
#pragma unroll
      for (int p2 = 0; p2 < 2; p2++) {
        float lo = sA[b2][2*p2], hi = sA[b2][2*p2+1];
        unsigned int r_;
        asm("v_cvt_pk_bf16_f32 %0, %1, %2" : "=v"(r_) : "v"(lo), "v"(hi));
        pk[b2][p2] = r_;
      }

    int src0 = ql + ((l >> 4) & 1) * 32;
    int src1 = src0 + 16;
    bool hi_half = (l & 32) != 0;
#pragma unroll
    for (int s = 0; s < 2; s++) {
      unsigned int a0 = __shfl((int)pk[2*s][0], src0);
      unsigned int a1 = __shfl((int)pk[2*s][1], src0);
      unsigned int a2 = __shfl((int)pk[2*s][0], src1);
      unsigned int a3 = __shfl((int)pk[2*s][1], src1);
      unsigned int c0 = __shfl((int)pk[2*s+1][0], src0);
      unsigned int c1 = __shfl((int)pk[2*s+1][1], src0);
      unsigned int c2 = __shfl((int)pk[2*s+1][0], src1);
      unsigned int c3 = __shfl((int)pk[2*s+1][1], src1);
      union { unsigned int u[4]; short8 s8; } pf;
      pf.u[0] = hi_half ? c0 : a0;
      pf.u[1] = hi_half ? c1 : a1;
      pf.u[2] = hi_half ? c2 : a2;
      pf.u[3] = hi_half ? c3 : a3;
#pragma unroll
      for (int db = 0; db < 18; db++) {
        int d = ql + 16*db;
        int col = (32*s + 8*g) ^ ((d & 7) << 3);
        short8 vf = *(const short8*)(vtL + d*64 + col);
        oA[db] = __builtin_amdgcn_mfma_f32_16x16x32_bf16(vf, pf.s8, oA[db], 0, 0, 0);
      }
    }
    __syncthreads();
  }

  float inv = 1.0f / lsum;
  int q = qt*QT + w*16 + ql;
  float* orow = Hf + (((size_t)b*NQL + q)*HN + h)*DV;
#pragma unroll
  for (int db = 0; db < 18; db++) {
    float4 st = make_float4(oA[db][0]*inv, oA[db][1]*inv, oA[db][2]*inv, oA[db][3]*inv);
    *(float4*)(orow + 16*db + 4*g) = st;
  }
}

// ---------------- Output projection (wave = 4 pos x 16 out-ch, comp-half split) ----------------
// hL per-position layout: [h][288] (256 mv: c*16+a, then 32 scalars).
// Channel ch = h*16+c lives at (ch>>4)*288 + (ch&15)*16; scalar jj = h*32+si at (jj>>5)*288+256+(jj&31).
#define HSTR 2308   // pos stride in hL
__global__ __launch_bounds__(256) void proj_o_kernel(
    const float* __restrict__ Hf,
    const float* __restrict__ ow_mv, const float* __restrict__ ow_s2mv, const float* __restrict__ ob_mv,
    const float* __restrict__ ow_mv2s, const float* __restrict__ ow_s2s, const float* __restrict__ ob_s,
    float* __restrict__ outp)
{
  __shared__ float hL[8*HSTR];
  int t = threadIdx.x;
  int p0 = blockIdx.x * 8;
  for (int i = t; i < 8*2304/4; i += 256) {
    int idx = i*4; int p = idx / 2304; int c = idx - p*2304;
    *(float4*)(hL + p*HSTR + c) = *(const float4*)(Hf + (size_t)(p0 + p)*2304 + c);
  }
  __syncthreads();

  int o = t & 15, pp = (t >> 4) & 7, half = t >> 7;
  const float* x = hL + pp*HSTR;
  float acc[8];
#pragma unroll
  for (int a = 0; a < 8; a++) acc[a] = 0.f;
  if (half == 0) acc[0] = ob_mv[o];

  if (half == 0) {
    for (int ch = 0; ch < 128; ch++) {
      const float* wrow = ow_mv + (size_t)(o*128 + ch)*9;
      const float* xc = x + (ch >> 4)*288 + (ch & 15)*16;   // FIXED: head stride is 288
      float w0 = wrow[0], w1 = wrow[1], w2 = wrow[2], w5 = wrow[5], w6 = wrow[6];
      float x0 = xc[0], x1 = xc[1], x2 = xc[2], x3 = xc[3];
      float x4 = xc[4], x5 = xc[5], x6 = xc[6], x7 = xc[7];
      acc[0] += w0*x0;                     // a=0 grade0
      acc[1] += w1*x1 + w5*x0;             // a=1: grade1 diag + e0<-comp0
      acc[2] += w1*x2;
      acc[3] += w1*x3;
      acc[4] += w1*x4;
      acc[5] += w2*x5 + w6*x2;             // a=5: grade2 diag + e0<-comp2
      acc[6] += w2*x6 + w6*x3;
      acc[7] += w2*x7 + w6*x4;
    }
    // s2mv into a=0
    for (int jj = 0; jj < 256; jj++)
      acc[0] += ow_s2mv[o*256 + jj] * x[(jj >> 5)*288 + 256 + (jj & 31)];   // FIXED
  } else {
    for (int ch = 0; ch < 128; ch++) {
      const float* wrow = ow_mv + (size_t)(o*128 + ch)*9;
      const float* xc = x + (ch >> 4)*288 + (ch & 15)*16 + 8;  // FIXED: comps 8..15
      float w2 = wrow[2], w3 = wrow[3], w4 = wrow[4], w7 = wrow[7], w8 = wrow[8];
      float x8 = xc[0], x9 = xc[1], x10 = xc[2], x11 = xc[3];
      float x12 = xc[4], x13 = xc[5], x14 = xc[6], x15 = xc[7];
      acc[0] += w2*x8;                     // a=8 grade2
      acc[1] += w2*x9;
      acc[2] += w2*x10;
      acc[3] += w3*x11 + w7*x8;            // a=11: grade3 diag + e0<-comp8
      acc[4] += w3*x12 + w7*x9;
      acc[5] += w3*x13 + w7*x10;
      acc[6] += w3*x14;
      acc[7] += w4*x15 + w8*x14;           // a=15: grade4 diag + e0<-comp14
    }
  }

  float* od = outp + (size_t)(p0 + pp)*256 + o*16 + half*8;
  *(float4*)(od)     = make_float4(acc[0], acc[1], acc[2], acc[3]);
  *(float4*)(od + 4) = make_float4(acc[4], acc[5], acc[6], acc[7]);

  // scalar outputs: remap threads -> (si, pos)
  int si = t & 31, ps = t >> 5;
  const float* xs = hL + ps*HSTR;
  float vs = ob_s[si];
  for (int ch = 0; ch < 128; ch++)
    vs += ow_mv2s[si*128 + ch] * xs[(ch >> 4)*288 + (ch & 15)*16];          // FIXED
  for (int jj = 0; jj < 256; jj++)
    vs += ow_s2s[si*256 + jj] * xs[(jj >> 5)*288 + 256 + (jj & 31)];        // FIXED
  float* out_s = outp + (size_t)NB*NQL*256;
  out_s[(size_t)(p0 + ps)*32 + si] = vs;
}

extern "C" void kernel_launch(void* const* d_in, const int* in_sizes, int n_in,
                              void* d_out, int out_size, void* d_ws, size_t ws_size,
                              hipStream_t stream)
{
  const float* mv_kv = (const float*)d_in[0];
  const float* mv_q  = (const float*)d_in[1];
  const float* s_kv  = (const float*)d_in[2];
  const float* s_q   = (const float*)d_in[3];

  ushort* Kf  = (ushort*)d_ws;                          // 4*2048*160   bf16
  ushort* VfT = Kf  + (size_t)NB*NKVL*DQK;              // 4*288*2048   bf16
  ushort* Qf  = VfT + (size_t)NB*DV*NKVL;               // 4*8*2048*160 bf16
  float*  Hf  = (float*)(Qf + (size_t)NB*HN*NQL*DQK);   // 4*2048*8*288 f32

  proj_kv_kernel<<<NB*NKVL/32, 256, 0, stream>>>(mv_kv, s_kv,
      (const float*)d_in[10], (const float*)d_in[11], (const float*)d_in[12],
      (const float*)d_in[13], (const float*)d_in[14], (const float*)d_in[15],
      (const float*)d_in[16], (const float*)d_in[17], (const float*)d_in[18],
      (const float*)d_in[19], (const float*)d_in[20], (const float*)d_in[21],
      Kf, VfT);
  proj_q_kernel<<<NB*NQL/16, 320, 0, stream>>>(mv_q, s_q,
      (const float*)d_in[4], (const float*)d_in[5], (const float*)d_in[6],
      (const float*)d_in[7], (const float*)d_in[8], (const float*)d_in[9],
      Qf);
  attn_kernel<<<NB*HN*(NQL/QT), 256, 0, stream>>>(Kf, VfT, Qf, Hf);
  proj_o_kernel<<<NB*NQL/8, 256, 0, stream>>>(Hf,
      (const float*)d_in[22], (const float*)d_in[23], (const float*)d_in[24],
      (const float*)d_in[25], (const float*)d_in[26], (const float*)d_in[27],
      (float*)d_out);
}

// Round 6
// 498.183 us; speedup vs baseline: 9.9436x; 1.0235x over previous
//
#include <hip/hip_runtime.h>
#include <hip/hip_bf16.h>
#include <math.h>

// Problem constants
#define NB   4
#define NQL  2048
#define NKVL 2048
#define HN   8
#define DQK  160    // qk feature dim
#define DV   288    // v feature dim
#define QT   128    // q rows per block (8 waves x 16)
#define KTL  64     // kv per tile
#define KLP  168    // K LDS row stride (bf16 elems)

#define SCALE 0.07905694150420949f   // 1/sqrt(160), folded into Q

typedef __attribute__((ext_vector_type(8))) short short8;
typedef __attribute__((ext_vector_type(4))) float f32x4;
typedef __attribute__((ext_vector_type(4))) int int4v;

__constant__ int c_grade[16] = {0,1,1,1,1,2,2,2,2,2,2,3,3,3,3,4};
__constant__ int c_inner[8]  = {0,2,3,4,8,9,10,14};
__constant__ int c_esrc[16]  = {-1,0,-1,-1,-1,2,3,4,-1,-1,-1,8,9,10,-1,14};
__constant__ int c_ey[16]    = {0,5,0,0,0,6,6,6,0,0,0,7,7,7,0,8};

__device__ __forceinline__ ushort f2bf(float v) {
  __hip_bfloat16 h = __float2bfloat16(v);
  union { __hip_bfloat16 b; ushort u; } cv; cv.b = h; return cv.u;
}

// ---------------- K/V projection (weight-stationary, 32 pos/block) ----------------
#define KWMV   0
#define KS2MV  2304
#define KMV2S  2816
#define KS2S   3328
#define KBMV   4352
#define KBS    4368
#define VWMV   4400
#define VS2MV  6704
#define VMV2S  7216
#define VS2S   7728
#define VBMV   8752
#define VBS    8768
#define WLSZ   8800
#define XSTR   289   // pos stride in xL
#define OSTR   456   // pos stride in oL (ushort)

__device__ __forceinline__ void kv_accum(const float* wL, const float* xL,
                                         int f, float acc[32]) {
  if (f < 160) {
    if (f < 128) {                      // K mv-feature
      int c = f >> 3, a = c_inner[f & 7], y = c_grade[a];
      float bias = (a == 0) ? wL[KBMV + c] : 0.f;
#pragma unroll
      for (int p = 0; p < 32; p++) acc[p] = bias;
      for (int ci = 0; ci < 16; ci++) {
        float w = wL[KWMV + (c*16 + ci)*9 + y];
#pragma unroll
        for (int p = 0; p < 32; p++) acc[p] += w * xL[p*XSTR + ci*16 + a];
      }
      if (a == 0) {
        for (int i2 = 0; i2 < 32; i2++) {
          float w = wL[KS2MV + c*32 + i2];
#pragma unroll
          for (int p = 0; p < 32; p++) acc[p] += w * xL[p*XSTR + 256 + i2];
        }
      }
    } else {                            // K scalar
      int si = f - 128;
      float bias = wL[KBS + si];
#pragma unroll
      for (int p = 0; p < 32; p++) acc[p] = bias;
      for (int ci = 0; ci < 16; ci++) {
        float w = wL[KMV2S + si*16 + ci];
#pragma unroll
        for (int p = 0; p < 32; p++) acc[p] += w * xL[p*XSTR + ci*16];
      }
      for (int i2 = 0; i2 < 32; i2++) {
        float w = wL[KS2S + si*32 + i2];
#pragma unroll
        for (int p = 0; p < 32; p++) acc[p] += w * xL[p*XSTR + 256 + i2];
      }
    }
  } else {
    int g = f - 160;
    if (g < 256) {                      // V mv-feature
      int c = g >> 4, a = g & 15, y = c_grade[a];
      float bias = (a == 0) ? wL[VBMV + c] : 0.f;
#pragma unroll
      for (int p = 0; p < 32; p++) acc[p] = bias;
      for (int ci = 0; ci < 16; ci++) {
        float w = wL[VWMV + (c*16 + ci)*9 + y];
#pragma unroll
        for (int p = 0; p < 32; p++) acc[p] += w * xL[p*XSTR + ci*16 + a];
      }
      int sa = c_esrc[a];
      if (sa >= 0) {
        int ey = c_ey[a];
        for (int ci = 0; ci < 16; ci++) {
          float w = wL[VWMV + (c*16 + ci)*9 + ey];
#pragma unroll
          for (int p = 0; p < 32; p++) acc[p] += w * xL[p*XSTR + ci*16 + sa];
        }
      }
      if (a == 0) {
        for (int i2 = 0; i2 < 32; i2++) {
          float w = wL[VS2MV + c*32 + i2];
#pragma unroll
          for (int p = 0; p < 32; p++) acc[p] += w * xL[p*XSTR + 256 + i2];
        }
      }
    } else {                            // V scalar
      int si = g - 256;
      float bias = wL[VBS + si];
#pragma unroll
      for (int p = 0; p < 32; p++) acc[p] = bias;
      for (int ci = 0; ci < 16; ci++) {
        float w = wL[VMV2S + si*16 + ci];
#pragma unroll
        for (int p = 0; p < 32; p++) acc[p] += w * xL[p*XSTR + ci*16];
      }
      for (int i2 = 0; i2 < 32; i2++) {
        float w = wL[VS2S + si*32 + i2];
#pragma unroll
        for (int p = 0; p < 32; p++) acc[p] += w * xL[p*XSTR + 256 + i2];
      }
    }
  }
}

__global__ __launch_bounds__(256) void proj_kv_kernel(
    const float* __restrict__ mv_kv, const float* __restrict__ s_kv,
    const float* __restrict__ kw_mv, const float* __restrict__ kw_s2mv, const float* __restrict__ kb_mv,
    const float* __restrict__ kw_mv2s, const float* __restrict__ kw_s2s, const float* __restrict__ kb_s,
    const float* __restrict__ vw_mv, const float* __restrict__ vw_s2mv, const float* __restrict__ vb_mv,
    const float* __restrict__ vw_mv2s, const float* __restrict__ vw_s2s, const float* __restrict__ vb_s,
    ushort* __restrict__ Kf, ushort* __restrict__ VfT)
{
  __shared__ float wL[WLSZ];
  __shared__ float xL[32*XSTR];
  int t = threadIdx.x;
  for (int i = t; i < 2304; i += 256) wL[KWMV + i] = kw_mv[i];
  for (int i = t; i < 512;  i += 256) wL[KS2MV + i] = kw_s2mv[i];
  for (int i = t; i < 512;  i += 256) wL[KMV2S + i] = kw_mv2s[i];
  for (int i = t; i < 1024; i += 256) wL[KS2S + i] = kw_s2s[i];
  if (t < 16) wL[KBMV + t] = kb_mv[t];
  if (t < 32) wL[KBS + t] = kb_s[t];
  for (int i = t; i < 2304; i += 256) wL[VWMV + i] = vw_mv[i];
  for (int i = t; i < 512;  i += 256) wL[VS2MV + i] = vw_s2mv[i];
  for (int i = t; i < 512;  i += 256) wL[VMV2S + i] = vw_mv2s[i];
  for (int i = t; i < 1024; i += 256) wL[VS2S + i] = vw_s2s[i];
  if (t < 16) wL[VBMV + t] = vb_mv[t];
  if (t < 32) wL[VBS + t] = vb_s[t];

  int p0 = blockIdx.x * 32;
  for (int i = t; i < 32*256; i += 256) {
    int p = i >> 8, c = i & 255;
    xL[p*XSTR + c] = mv_kv[(size_t)(p0 + p)*256 + c];
  }
  for (int i = t; i < 32*32; i += 256) {
    int p = i >> 5, c = i & 31;
    xL[p*XSTR + 256 + c] = s_kv[(size_t)(p0 + p)*32 + c];
  }
  __syncthreads();

  float acc0[32], acc1[32];
  kv_accum(wL, xL, t, acc0);
  if (t < 192) kv_accum(wL, xL, 256 + t, acc1);
  __syncthreads();

  ushort* oL = (ushort*)xL;
#pragma unroll
  for (int p = 0; p < 32; p++) oL[p*OSTR + t] = f2bf(acc0[p]);
  if (t < 192) {
#pragma unroll
    for (int p = 0; p < 32; p++) oL[p*OSTR + 256 + t] = f2bf(acc1[p]);
  }
  __syncthreads();

  int b = p0 >> 11, kv0 = p0 & 2047;
  for (int it = 0; it < 10; it++) {
    int j = t + it*256;
    int p = j / 80, fp = j - p*80;
    uint u = (uint)oL[p*OSTR + 2*fp] | ((uint)oL[p*OSTR + 2*fp + 1] << 16);
    *(uint*)(Kf + (size_t)(p0 + p)*DQK + 2*fp) = u;
  }
  for (int it = 0; it < 18; it++) {
    int j = t + it*256;
    int g = j >> 4, pp = j & 15;
    uint u = (uint)oL[(2*pp)*OSTR + 160 + g] | ((uint)oL[(2*pp+1)*OSTR + 160 + g] << 16);
    *(uint*)(VfT + ((size_t)b*DV + g)*NKVL + kv0 + 2*pp) = u;
  }
}

// ---------------- Q projection (shared-x across heads, 16 pos/block) ----------------
__global__ __launch_bounds__(320) void proj_q_kernel(
    const float* __restrict__ mv_q, const float* __restrict__ s_q,
    const float* __restrict__ qw_mv, const float* __restrict__ qw_s2mv, const float* __restrict__ qb_mv,
    const float* __restrict__ qw_mv2s, const float* __restrict__ qw_s2s, const float* __restrict__ qb_s,
    ushort* __restrict__ Qf)
{
  __shared__ float xL[16*XSTR];
  int t = threadIdx.x;
  int p0 = blockIdx.x * 16;
  for (int i = t; i < 16*256; i += 320) {
    int p = i >> 8, c = i & 255;
    xL[p*XSTR + c] = mv_q[(size_t)(p0 + p)*256 + c];
  }
  for (int i = t; i < 16*32; i += 320) {
    int p = i >> 5, c = i & 31;
    xL[p*XSTR + 256 + c] = s_q[(size_t)(p0 + p)*32 + c];
  }
  __syncthreads();

  int f0 = t % 160;
  int h0 = t / 160;
  float acc[4][16];

  if (f0 < 128) {
    int c = f0 >> 3, a = c_inner[f0 & 7], y = c_grade[a];
    int o0 = c*HN + h0, o1 = o0 + 2, o2 = o0 + 4, o3 = o0 + 6;
#pragma unroll
    for (int p = 0; p < 16; p++) {
      acc[0][p] = (a == 0) ? qb_mv[o0] : 0.f;
      acc[1][p] = (a == 0) ? qb_mv[o1] : 0.f;
      acc[2][p] = (a == 0) ? qb_mv[o2] : 0.f;
      acc[3][p] = (a == 0) ? qb_mv[o3] : 0.f;
    }
    for (int ci = 0; ci < 16; ci++) {
      float w0 = qw_mv[(o0*16 + ci)*9 + y];
      float w1 = qw_mv[(o1*16 + ci)*9 + y];
      float w2 = qw_mv[(o2*16 + ci)*9 + y];
      float w3 = qw_mv[(o3*16 + ci)*9 + y];
#pragma unroll
      for (int p = 0; p < 16; p++) {
        float xv = xL[p*XSTR + ci*16 + a];
        acc[0][p] += w0*xv; acc[1][p] += w1*xv;
        acc[2][p] += w2*xv; acc[3][p] += w3*xv;
      }
    }
    if (a == 0) {
      for (int i2 = 0; i2 < 32; i2++) {
        float w0 = qw_s2mv[o0*32 + i2];
        float w1 = qw_s2mv[o1*32 + i2];
        float w2 = qw_s2mv[o2*32 + i2];
        float w3 = qw_s2mv[o3*32 + i2];
#pragma unroll
        for (int p = 0; p < 16; p++) {
          float xv = xL[p*XSTR + 256 + i2];
          acc[0][p] += w0*xv; acc[1][p] += w1*xv;
          acc[2][p] += w2*xv; acc[3][p] += w3*xv;
        }
      }
    }
  } else {
    int si = f0 - 128;
    int o0 = si*HN + h0, o1 = o0 + 2, o2 = o0 + 4, o3 = o0 + 6;
#pragma unroll
    for (int p = 0; p < 16; p++) {
      acc[0][p] = qb_s[o0]; acc[1][p] = qb_s[o1];
      acc[2][p] = qb_s[o2]; acc[3][p] = qb_s[o3];
    }
    for (int ci = 0; ci < 16; ci++) {
      float w0 = qw_mv2s[o0*16 + ci];
      float w1 = qw_mv2s[o1*16 + ci];
      float w2 = qw_mv2s[o2*16 + ci];
      float w3 = qw_mv2s[o3*16 + ci];
#pragma unroll
      for (int p = 0; p < 16; p++) {
        float xv = xL[p*XSTR + ci*16];
        acc[0][p] += w0*xv; acc[1][p] += w1*xv;
        acc[2][p] += w2*xv; acc[3][p] += w3*xv;
      }
    }
    for (int i2 = 0; i2 < 32; i2++) {
      float w0 = qw_s2s[o0*32 + i2];
      float w1 = qw_s2s[o1*32 + i2];
      float w2 = qw_s2s[o2*32 + i2];
      float w3 = qw_s2s[o3*32 + i2];
#pragma unroll
      for (int p = 0; p < 16; p++) {
        float xv = xL[p*XSTR + 256 + i2];
        acc[0][p] += w0*xv; acc[1][p] += w1*xv;
        acc[2][p] += w2*xv; acc[3][p] += w3*xv;
      }
    }
  }

  int b = p0 >> 11, q0 = p0 & 2047;
#pragma unroll
  for (int k = 0; k < 4; k++) {
    int h = h0 + 2*k;
    ushort* qdst = Qf + ((size_t)(b*HN + h)*NQL + q0)*DQK + f0;
#pragma unroll
    for (int p = 0; p < 16; p++)
      qdst[p*DQK] = f2bf(acc[k][p] * SCALE);
  }
}

// ---------------- MFMA flash attention (QT=128, 8 waves, defer-rescale, setprio) ----------------
__global__ __launch_bounds__(512, 4) void attn_kernel(
    const ushort* __restrict__ Kf,   // [b][2048][160]
    const ushort* __restrict__ VfT,  // [b][288][2048]
    const ushort* __restrict__ Qf,   // [bh][2048][160] (scaled)
    float* __restrict__ Hf)          // [b][q][h][288]
{
  __shared__ ushort kL[KTL*KLP];
  __shared__ ushort vtL[DV*KTL];

  const int NT = NQL/QT;             // 16
  int bh = blockIdx.x / NT;
  int qt = blockIdx.x - bh*NT;
  int b = bh >> 3, h = bh & 7;
  int t = threadIdx.x, w = t >> 6, l = t & 63;
  int ql = l & 15, g = l >> 4;

  const ushort* qrow = Qf + ((size_t)bh*NQL + (size_t)qt*QT + w*16 + ql)*DQK + g*8;
  short8 qf[5];
#pragma unroll
  for (int ks = 0; ks < 5; ks++)
    qf[ks] = *(const short8*)(qrow + ks*32);

  f32x4 oA[18];
#pragma unroll
  for (int i = 0; i < 18; i++) oA[i] = (f32x4)(0.f);
  float m = -INFINITY, lsum = 0.f;

  const ushort* kb = Kf  + (size_t)b*NKVL*DQK;
  const ushort* vb = VfT + (size_t)b*DV*NKVL;

  for (int kt0 = 0; kt0 < NKVL; kt0 += KTL) {
    // stage K tile: 1280 16B-chunks over 512 threads
#pragma unroll
    for (int it = 0; it < 3; it++) {
      int i = t + it*512;
      if (i < 1280) {
        int r = i / 20, c = i - r*20;
        int4v val = *(const int4v*)(kb + (size_t)(kt0 + r)*DQK + c*8);
        *(int4v*)(kL + r*KLP + c*8) = val;
      }
    }
    // stage V^T tile: 2304 chunks; XOR swizzle
#pragma unroll
    for (int it = 0; it < 5; it++) {
      int i = t + it*512;
      if (i < 2304) {
        int d = i >> 3, c = i & 7;
        int4v val = *(const int4v*)(vb + (size_t)d*NKVL + kt0 + c*8);
        int col = (c*8) ^ ((d & 7) << 3);
        *(int4v*)(vtL + d*64 + col) = val;
      }
    }
    __syncthreads();

    // scores S^T: 4 tiles (16kv x 16q)
    f32x4 sA[4];
    __builtin_amdgcn_s_setprio(1);
#pragma unroll
    for (int kvb = 0; kvb < 4; kvb++) {
      sA[kvb] = (f32x4)(0.f);
      const ushort* krow = kL + (ql + 16*kvb)*KLP + g*8;
#pragma unroll
      for (int ks = 0; ks < 5; ks++) {
        short8 kf = *(const short8*)(krow + ks*32);
        sA[kvb] = __builtin_amdgcn_mfma_f32_16x16x32_bf16(kf, qf[ks], sA[kvb], 0, 0, 0);
      }
    }
    __builtin_amdgcn_s_setprio(0);

    // online softmax with defer-rescale (T13, THR=8)
    float tm = sA[0][0];
#pragma unroll
    for (int kvb = 0; kvb < 4; kvb++)
#pragma unroll
      for (int r = 0; r < 4; r++) tm = fmaxf(tm, sA[kvb][r]);
    tm = fmaxf(tm, __shfl_xor(tm, 16));
    tm = fmaxf(tm, __shfl_xor(tm, 32));
    if (!__all(tm - m <= 8.0f)) {
      float nm = fmaxf(m, tm);
      float ef = __expf(m - nm);    // first tile: exp(-inf) = 0
      lsum *= ef;
#pragma unroll
      for (int i = 0; i < 18; i++) {
        oA[i][0] *= ef; oA[i][1] *= ef; oA[i][2] *= ef; oA[i][3] *= ef;
      }
      m = nm;
    }
    float rs = 0.f;
#pragma unroll
    for (int kvb = 0; kvb < 4; kvb++)
#pragma unroll
      for (int r = 0; r < 4; r++) {
        float p = __expf(sA[kvb][r] - m);
        sA[kvb][r] = p;
        rs += p;
      }
    rs += __shfl_xor(rs, 16);
    rs += __shfl_xor(rs, 32);
    lsum += rs;

    // pack P -> bf16 pairs
    unsigned int pk[4][2];
#pragma unroll
    for (int b2 = 0; b2 < 4; b2++)
#pragma unroll
      for (int p2 = 0; p2 < 2; p2++) {
        float lo = sA[b2][2*p2], hi = sA[b2][2*p2+1];
        unsigned int r_;
        asm("v_cvt_pk_bf16_f32 %0, %1, %2" : "=v"(r_) : "v"(lo), "v"(hi));
        pk[b2][p2] = r_;
      }

    int src0 = ql + ((l >> 4) & 1) * 32;
    int src1 = src0 + 16;
    bool hi_half = (l & 32) != 0;
#pragma unroll
    for (int s = 0; s < 2; s++) {
      unsigned int a0 = __shfl((int)pk[2*s][0], src0);
      unsigned int a1 = __shfl((int)pk[2*s][1], src0);
      unsigned int a2 = __shfl((int)pk[2*s][0], src1);
      unsigned int a3 = __shfl((int)pk[2*s][1], src1);
      unsigned int c0 = __shfl((int)pk[2*s+1][0], src0);
      unsigned int c1 = __shfl((int)pk[2*s+1][1], src0);
      unsigned int c2 = __shfl((int)pk[2*s+1][0], src1);
      unsigned int c3 = __shfl((int)pk[2*s+1][1], src1);
      union { unsigned int u[4]; short8 s8; } pf;
      pf.u[0] = hi_half ? c0 : a0;
      pf.u[1] = hi_half ? c1 : a1;
      pf.u[2] = hi_half ? c2 : a2;
      pf.u[3] = hi_half ? c3 : a3;
      __builtin_amdgcn_s_setprio(1);
#pragma unroll
      for (int db = 0; db < 18; db++) {
        int d = ql + 16*db;
        int col = (32*s + 8*g) ^ ((d & 7) << 3);
        short8 vf = *(const short8*)(vtL + d*64 + col);
        oA[db] = __builtin_amdgcn_mfma_f32_16x16x32_bf16(vf, pf.s8, oA[db], 0, 0, 0);
      }
      __builtin_amdgcn_s_setprio(0);
    }
    __syncthreads();
  }

  float inv = 1.0f / lsum;
  int q = qt*QT + w*16 + ql;
  float* orow = Hf + (((size_t)b*NQL + q)*HN + h)*DV;
#pragma unroll
  for (int db = 0; db < 18; db++) {
    float4 st = make_float4(oA[db][0]*inv, oA[db][1]*inv, oA[db][2]*inv, oA[db][3]*inv);
    *(float4*)(orow + 16*db + 4*g) = st;
  }
}

// ---------------- O-weight transpose prep ----------------
// owT regions (floats):
//   [0,18432)      mvT[y][ch][o]   = ow_mv[(o*128+ch)*9 + y]
//   [18432,22528)  s2mvT[jj][o]    = ow_s2mv[o*256 + jj]
//   [22528,26624)  mv2sT[ch][si]   = ow_mv2s[si*128 + ch]
//   [26624,34816)  s2sT[jj][si]    = ow_s2s[si*256 + jj]
#define OWT_SZ 34816
__global__ __launch_bounds__(256) void prep_ow_kernel(
    const float* __restrict__ ow_mv, const float* __restrict__ ow_s2mv,
    const float* __restrict__ ow_mv2s, const float* __restrict__ ow_s2s,
    float* __restrict__ owT)
{
  int i = blockIdx.x*256 + threadIdx.x;
  if (i < 18432) {
    int y = i / 2048, r = i & 2047, ch = r >> 4, o = r & 15;
    owT[i] = ow_mv[(size_t)(o*128 + ch)*9 + y];
  } else if (i < 22528) {
    int r = i - 18432, jj = r >> 4, o = r & 15;
    owT[i] = ow_s2mv[o*256 + jj];
  } else if (i < 26624) {
    int r = i - 22528, ch = r >> 5, si = r & 31;
    owT[i] = ow_mv2s[si*128 + ch];
  } else if (i < OWT_SZ) {
    int r = i - 26624, jj = r >> 5, si = r & 31;
    owT[i] = ow_s2s[si*256 + jj];
  }
}

// ---------------- Output projection (coalesced transposed weights) ----------------
#define HSTR 2308
__global__ __launch_bounds__(256) void proj_o_kernel(
    const float* __restrict__ Hf,
    const float* __restrict__ owT,
    const float* __restrict__ ob_mv, const float* __restrict__ ob_s,
    float* __restrict__ outp)
{
  __shared__ float hL[8*HSTR];
  int t = threadIdx.x;
  int p0 = blockIdx.x * 8;
  for (int i = t; i < 8*2304/4; i += 256) {
    int idx = i*4; int p = idx / 2304; int c = idx - p*2304;
    *(float4*)(hL + p*HSTR + c) = *(const float4*)(Hf + (size_t)(p0 + p)*2304 + c);
  }
  __syncthreads();

  const float* mvT   = owT;            // [y][ch][o]: y*2048 + ch*16 + o
  const float* s2mvT = owT + 18432;    // jj*16 + o
  const float* mv2sT = owT + 22528;    // ch*32 + si
  const float* s2sT  = owT + 26624;    // jj*32 + si

  int o = t & 15, pp = (t >> 4) & 7, half = t >> 7;
  const float* x = hL + pp*HSTR;
  float acc[8];
#pragma unroll
  for (int a = 0; a < 8; a++) acc[a] = 0.f;
  if (half == 0) acc[0] = ob_mv[o];

  if (half == 0) {
    for (int ch = 0; ch < 128; ch++) {
      const float* xc = x + (ch >> 4)*288 + (ch & 15)*16;
      float w0 = mvT[0*2048 + ch*16 + o], w1 = mvT[1*2048 + ch*16 + o];
      float w2 = mvT[2*2048 + ch*16 + o];
      float w5 = mvT[5*2048 + ch*16 + o], w6 = mvT[6*2048 + ch*16 + o];
      float x0 = xc[0], x1 = xc[1], x2 = xc[2], x3 = xc[3];
      float x4 = xc[4], x5 = xc[5], x6 = xc[6], x7 = xc[7];
      acc[0] += w0*x0;
      acc[1] += w1*x1 + w5*x0;
      acc[2] += w1*x2;
      acc[3] += w1*x3;
      acc[4] += w1*x4;
      acc[5] += w2*x5 + w6*x2;
      acc[6] += w2*x6 + w6*x3;
      acc[7] += w2*x7 + w6*x4;
    }
    for (int jj = 0; jj < 256; jj++)
      acc[0] += s2mvT[jj*16 + o] * x[(jj >> 5)*288 + 256 + (jj & 31)];
  } else {
    for (int ch = 0; ch < 128; ch++) {
      const float* xc = x + (ch >> 4)*288 + (ch & 15)*16 + 8;
      float w2 = mvT[2*2048 + ch*16 + o], w3 = mvT[3*2048 + ch*16 + o];
      float w4 = mvT[4*2048 + ch*16 + o];
      float w7 = mvT[7*2048 + ch*16 + o], w8 = mvT[8*2048 + ch*16 + o];
      float x8 = xc[0], x9 = xc[1], x10 = xc[2], x11 = xc[3];
      float x12 = xc[4], x13 = xc[5], x14 = xc[6], x15 = xc[7];
      acc[0] += w2*x8;
      acc[1] += w2*x9;
      acc[2] += w2*x10;
      acc[3] += w3*x11 + w7*x8;
      acc[4] += w3*x12 + w7*x9;
      acc[5] += w3*x13 + w7*x10;
      acc[6] += w3*x14;
      acc[7] += w4*x15 + w8*x14;
    }
  }

  float* od = outp + (size_t)(p0 + pp)*256 + o*16 + half*8;
  *(float4*)(od)     = make_float4(acc[0], acc[1], acc[2], acc[3]);
  *(float4*)(od + 4) = make_float4(acc[4], acc[5], acc[6], acc[7]);

  // scalar outputs
  int si = t & 31, ps = t >> 5;
  const float* xs = hL + ps*HSTR;
  float vs = ob_s[si];
  for (int ch = 0; ch < 128; ch++)
    vs += mv2sT[ch*32 + si] * xs[(ch >> 4)*288 + (ch & 15)*16];
  for (int jj = 0; jj < 256; jj++)
    vs += s2sT[jj*32 + si] * xs[(jj >> 5)*288 + 256 + (jj & 31)];
  float* out_s = outp + (size_t)NB*NQL*256;
  out_s[(size_t)(p0 + ps)*32 + si] = vs;
}

extern "C" void kernel_launch(void* const* d_in, const int* in_sizes, int n_in,
                              void* d_out, int out_size, void* d_ws, size_t ws_size,
                              hipStream_t stream)
{
  const float* mv_kv = (const float*)d_in[0];
  const float* mv_q  = (const float*)d_in[1];
  const float* s_kv  = (const float*)d_in[2];
  const float* s_q   = (const float*)d_in[3];

  ushort* Kf  = (ushort*)d_ws;                          // 4*2048*160   bf16
  ushort* VfT = Kf  + (size_t)NB*NKVL*DQK;              // 4*288*2048   bf16
  ushort* Qf  = VfT + (size_t)NB*DV*NKVL;               // 4*8*2048*160 bf16
  float*  Hf  = (float*)(Qf + (size_t)NB*HN*NQL*DQK);   // 4*2048*8*288 f32
  float*  owT = Hf + (size_t)NB*NQL*HN*DV;              // 34816 f32

  prep_ow_kernel<<<(OWT_SZ + 255)/256, 256, 0, stream>>>(
      (const float*)d_in[22], (const float*)d_in[23],
      (const float*)d_in[25], (const float*)d_in[26], owT);
  proj_kv_kernel<<<NB*NKVL/32, 256, 0, stream>>>(mv_kv, s_kv,
      (const float*)d_in[10], (const float*)d_in[11], (const float*)d_in[12],
      (const float*)d_in[13], (const float*)d_in[14], (const float*)d_in[15],
      (const float*)d_in[16], (const float*)d_in[17], (const float*)d_in[18],
      (const float*)d_in[19], (const float*)d_in[20], (const float*)d_in[21],
      Kf, VfT);
  proj_q_kernel<<<NB*NQL/16, 320, 0, stream>>>(mv_q, s_q,
      (const float*)d_in[4], (const float*)d_in[5], (const float*)d_in[6],
      (const float*)d_in[7], (const float*)d_in[8], (const float*)d_in[9],
      Qf);
  attn_kernel<<<NB*HN*(NQL/QT), 512, 0, stream>>>(Kf, VfT, Qf, Hf);
  proj_o_kernel<<<NB*NQL/8, 256, 0, stream>>>(Hf, owT,
      (const float*)d_in[24], (const float*)d_in[27],
      (float*)d_out);
}

// Round 7
// 472.255 us; speedup vs baseline: 10.4896x; 1.0549x over previous
//
#include <hip/hip_runtime.h>
#include <hip/hip_bf16.h>
#include <math.h>

// Problem constants
#define NB   4
#define NQL  2048
#define NKVL 2048
#define HN   8
#define DQK  160    // qk feature dim
#define DV   288    // v feature dim
#define QT   128    // q rows per block (8 waves x 16)
#define KTL  64     // kv per tile
#define KLP  168    // K LDS row stride (bf16 elems)

#define SCALE 0.07905694150420949f   // 1/sqrt(160), folded into Q

typedef __attribute__((ext_vector_type(8))) short short8;
typedef __attribute__((ext_vector_type(4))) float f32x4;
typedef __attribute__((ext_vector_type(4))) int int4v;

__constant__ int c_grade[16] = {0,1,1,1,1,2,2,2,2,2,2,3,3,3,3,4};
__constant__ int c_inner[8]  = {0,2,3,4,8,9,10,14};
__constant__ int c_esrc[16]  = {-1,0,-1,-1,-1,2,3,4,-1,-1,-1,8,9,10,-1,14};
__constant__ int c_ey[16]    = {0,5,0,0,0,6,6,6,0,0,0,7,7,7,0,8};

__device__ __forceinline__ ushort f2bf(float v) {
  __hip_bfloat16 h = __float2bfloat16(v);
  union { __hip_bfloat16 b; ushort u; } cv; cv.b = h; return cv.u;
}

// ---------------- K/V projection (weight-stationary, 32 pos/block) ----------------
#define KWMV   0
#define KS2MV  2304
#define KMV2S  2816
#define KS2S   3328
#define KBMV   4352
#define KBS    4368
#define VWMV   4400
#define VS2MV  6704
#define VMV2S  7216
#define VS2S   7728
#define VBMV   8752
#define VBS    8768
#define WLSZ   8800
#define XSTR   289   // pos stride in xL
#define OSTR   456   // pos stride in oL (ushort)

__device__ __forceinline__ void kv_accum(const float* wL, const float* xL,
                                         int f, float acc[32]) {
  if (f < 160) {
    if (f < 128) {                      // K mv-feature
      int c = f >> 3, a = c_inner[f & 7], y = c_grade[a];
      float bias = (a == 0) ? wL[KBMV + c] : 0.f;
#pragma unroll
      for (int p = 0; p < 32; p++) acc[p] = bias;
      for (int ci = 0; ci < 16; ci++) {
        float w = wL[KWMV + (c*16 + ci)*9 + y];
#pragma unroll
        for (int p = 0; p < 32; p++) acc[p] += w * xL[p*XSTR + ci*16 + a];
      }
      if (a == 0) {
        for (int i2 = 0; i2 < 32; i2++) {
          float w = wL[KS2MV + c*32 + i2];
#pragma unroll
          for (int p = 0; p < 32; p++) acc[p] += w * xL[p*XSTR + 256 + i2];
        }
      }
    } else {                            // K scalar
      int si = f - 128;
      float bias = wL[KBS + si];
#pragma unroll
      for (int p = 0; p < 32; p++) acc[p] = bias;
      for (int ci = 0; ci < 16; ci++) {
        float w = wL[KMV2S + si*16 + ci];
#pragma unroll
        for (int p = 0; p < 32; p++) acc[p] += w * xL[p*XSTR + ci*16];
      }
      for (int i2 = 0; i2 < 32; i2++) {
        float w = wL[KS2S + si*32 + i2];
#pragma unroll
        for (int p = 0; p < 32; p++) acc[p] += w * xL[p*XSTR + 256 + i2];
      }
    }
  } else {
    int g = f - 160;
    if (g < 256) {                      // V mv-feature
      int c = g >> 4, a = g & 15, y = c_grade[a];
      float bias = (a == 0) ? wL[VBMV + c] : 0.f;
#pragma unroll
      for (int p = 0; p < 32; p++) acc[p] = bias;
      for (int ci = 0; ci < 16; ci++) {
        float w = wL[VWMV + (c*16 + ci)*9 + y];
#pragma unroll
        for (int p = 0; p < 32; p++) acc[p] += w * xL[p*XSTR + ci*16 + a];
      }
      int sa = c_esrc[a];
      if (sa >= 0) {
        int ey = c_ey[a];
        for (int ci = 0; ci < 16; ci++) {
          float w = wL[VWMV + (c*16 + ci)*9 + ey];
#pragma unroll
          for (int p = 0; p < 32; p++) acc[p] += w * xL[p*XSTR + ci*16 + sa];
        }
      }
      if (a == 0) {
        for (int i2 = 0; i2 < 32; i2++) {
          float w = wL[VS2MV + c*32 + i2];
#pragma unroll
          for (int p = 0; p < 32; p++) acc[p] += w * xL[p*XSTR + 256 + i2];
        }
      }
    } else {                            // V scalar
      int si = g - 256;
      float bias = wL[VBS + si];
#pragma unroll
      for (int p = 0; p < 32; p++) acc[p] = bias;
      for (int ci = 0; ci < 16; ci++) {
        float w = wL[VMV2S + si*16 + ci];
#pragma unroll
        for (int p = 0; p < 32; p++) acc[p] += w * xL[p*XSTR + ci*16];
      }
      for (int i2 = 0; i2 < 32; i2++) {
        float w = wL[VS2S + si*32 + i2];
#pragma unroll
        for (int p = 0; p < 32; p++) acc[p] += w * xL[p*XSTR + 256 + i2];
      }
    }
  }
}

__global__ __launch_bounds__(256) void proj_kv_kernel(
    const float* __restrict__ mv_kv, const float* __restrict__ s_kv,
    const float* __restrict__ kw_mv, const float* __restrict__ kw_s2mv, const float* __restrict__ kb_mv,
    const float* __restrict__ kw_mv2s, const float* __restrict__ kw_s2s, const float* __restrict__ kb_s,
    const float* __restrict__ vw_mv, const float* __restrict__ vw_s2mv, const float* __restrict__ vb_mv,
    const float* __restrict__ vw_mv2s, const float* __restrict__ vw_s2s, const float* __restrict__ vb_s,
    ushort* __restrict__ Kf, ushort* __restrict__ VfT)
{
  __shared__ float wL[WLSZ];
  __shared__ float xL[32*XSTR];
  int t = threadIdx.x;
  for (int i = t; i < 2304; i += 256) wL[KWMV + i] = kw_mv[i];
  for (int i = t; i < 512;  i += 256) wL[KS2MV + i] = kw_s2mv[i];
  for (int i = t; i < 512;  i += 256) wL[KMV2S + i] = kw_mv2s[i];
  for (int i = t; i < 1024; i += 256) wL[KS2S + i] = kw_s2s[i];
  if (t < 16) wL[KBMV + t] = kb_mv[t];
  if (t < 32) wL[KBS + t] = kb_s[t];
  for (int i = t; i < 2304; i += 256) wL[VWMV + i] = vw_mv[i];
  for (int i = t; i < 512;  i += 256) wL[VS2MV + i] = vw_s2mv[i];
  for (int i = t; i < 512;  i += 256) wL[VMV2S + i] = vw_mv2s[i];
  for (int i = t; i < 1024; i += 256) wL[VS2S + i] = vw_s2s[i];
  if (t < 16) wL[VBMV + t] = vb_mv[t];
  if (t < 32) wL[VBS + t] = vb_s[t];

  int p0 = blockIdx.x * 32;
  for (int i = t; i < 32*256; i += 256) {
    int p = i >> 8, c = i & 255;
    xL[p*XSTR + c] = mv_kv[(size_t)(p0 + p)*256 + c];
  }
  for (int i = t; i < 32*32; i += 256) {
    int p = i >> 5, c = i & 31;
    xL[p*XSTR + 256 + c] = s_kv[(size_t)(p0 + p)*32 + c];
  }
  __syncthreads();

  float acc0[32], acc1[32];
  kv_accum(wL, xL, t, acc0);
  if (t < 192) kv_accum(wL, xL, 256 + t, acc1);
  __syncthreads();

  ushort* oL = (ushort*)xL;
#pragma unroll
  for (int p = 0; p < 32; p++) oL[p*OSTR + t] = f2bf(acc0[p]);
  if (t < 192) {
#pragma unroll
    for (int p = 0; p < 32; p++) oL[p*OSTR + 256 + t] = f2bf(acc1[p]);
  }
  __syncthreads();

  int b = p0 >> 11, kv0 = p0 & 2047;
  for (int it = 0; it < 10; it++) {
    int j = t + it*256;
    int p = j / 80, fp = j - p*80;
    uint u = (uint)oL[p*OSTR + 2*fp] | ((uint)oL[p*OSTR + 2*fp + 1] << 16);
    *(uint*)(Kf + (size_t)(p0 + p)*DQK + 2*fp) = u;
  }
  for (int it = 0; it < 18; it++) {
    int j = t + it*256;
    int g = j >> 4, pp = j & 15;
    uint u = (uint)oL[(2*pp)*OSTR + 160 + g] | ((uint)oL[(2*pp+1)*OSTR + 160 + g] << 16);
    *(uint*)(VfT + ((size_t)b*DV + g)*NKVL + kv0 + 2*pp) = u;
  }
}

// ---------------- Q projection (shared-x across heads, 16 pos/block) ----------------
__global__ __launch_bounds__(320) void proj_q_kernel(
    const float* __restrict__ mv_q, const float* __restrict__ s_q,
    const float* __restrict__ qw_mv, const float* __restrict__ qw_s2mv, const float* __restrict__ qb_mv,
    const float* __restrict__ qw_mv2s, const float* __restrict__ qw_s2s, const float* __restrict__ qb_s,
    ushort* __restrict__ Qf)
{
  __shared__ float xL[16*XSTR];
  int t = threadIdx.x;
  int p0 = blockIdx.x * 16;
  for (int i = t; i < 16*256; i += 320) {
    int p = i >> 8, c = i & 255;
    xL[p*XSTR + c] = mv_q[(size_t)(p0 + p)*256 + c];
  }
  for (int i = t; i < 16*32; i += 320) {
    int p = i >> 5, c = i & 31;
    xL[p*XSTR + 256 + c] = s_q[(size_t)(p0 + p)*32 + c];
  }
  __syncthreads();

  int f0 = t % 160;
  int h0 = t / 160;
  float acc[4][16];

  if (f0 < 128) {
    int c = f0 >> 3, a = c_inner[f0 & 7], y = c_grade[a];
    int o0 = c*HN + h0, o1 = o0 + 2, o2 = o0 + 4, o3 = o0 + 6;
#pragma unroll
    for (int p = 0; p < 16; p++) {
      acc[0][p] = (a == 0) ? qb_mv[o0] : 0.f;
      acc[1][p] = (a == 0) ? qb_mv[o1] : 0.f;
      acc[2][p] = (a == 0) ? qb_mv[o2] : 0.f;
      acc[3][p] = (a == 0) ? qb_mv[o3] : 0.f;
    }
    for (int ci = 0; ci < 16; ci++) {
      float w0 = qw_mv[(o0*16 + ci)*9 + y];
      float w1 = qw_mv[(o1*16 + ci)*9 + y];
      float w2 = qw_mv[(o2*16 + ci)*9 + y];
      float w3 = qw_mv[(o3*16 + ci)*9 + y];
#pragma unroll
      for (int p = 0; p < 16; p++) {
        float xv = xL[p*XSTR + ci*16 + a];
        acc[0][p] += w0*xv; acc[1][p] += w1*xv;
        acc[2][p] += w2*xv; acc[3][p] += w3*xv;
      }
    }
    if (a == 0) {
      for (int i2 = 0; i2 < 32; i2++) {
        float w0 = qw_s2mv[o0*32 + i2];
        float w1 = qw_s2mv[o1*32 + i2];
        float w2 = qw_s2mv[o2*32 + i2];
        float w3 = qw_s2mv[o3*32 + i2];
#pragma unroll
        for (int p = 0; p < 16; p++) {
          float xv = xL[p*XSTR + 256 + i2];
          acc[0][p] += w0*xv; acc[1][p] += w1*xv;
          acc[2][p] += w2*xv; acc[3][p] += w3*xv;
        }
      }
    }
  } else {
    int si = f0 - 128;
    int o0 = si*HN + h0, o1 = o0 + 2, o2 = o0 + 4, o3 = o0 + 6;
#pragma unroll
    for (int p = 0; p < 16; p++) {
      acc[0][p] = qb_s[o0]; acc[1][p] = qb_s[o1];
      acc[2][p] = qb_s[o2]; acc[3][p] = qb_s[o3];
    }
    for (int ci = 0; ci < 16; ci++) {
      float w0 = qw_mv2s[o0*16 + ci];
      float w1 = qw_mv2s[o1*16 + ci];
      float w2 = qw_mv2s[o2*16 + ci];
      float w3 = qw_mv2s[o3*16 + ci];
#pragma unroll
      for (int p = 0; p < 16; p++) {
        float xv = xL[p*XSTR + ci*16];
        acc[0][p] += w0*xv; acc[1][p] += w1*xv;
        acc[2][p] += w2*xv; acc[3][p] += w3*xv;
      }
    }
    for (int i2 = 0; i2 < 32; i2++) {
      float w0 = qw_s2s[o0*32 + i2];
      float w1 = qw_s2s[o1*32 + i2];
      float w2 = qw_s2s[o2*32 + i2];
      float w3 = qw_s2s[o3*32 + i2];
#pragma unroll
      for (int p = 0; p < 16; p++) {
        float xv = xL[p*XSTR + 256 + i2];
        acc[0][p] += w0*xv; acc[1][p] += w1*xv;
        acc[2][p] += w2*xv; acc[3][p] += w3*xv;
      }
    }
  }

  int b = p0 >> 11, q0 = p0 & 2047;
#pragma unroll
  for (int k = 0; k < 4; k++) {
    int h = h0 + 2*k;
    ushort* qdst = Qf + ((size_t)(b*HN + h)*NQL + q0)*DQK + f0;
#pragma unroll
    for (int p = 0; p < 16; p++)
      qdst[p*DQK] = f2bf(acc[k][p] * SCALE);
  }
}

// ---------------- MFMA flash attention (QT=128, 8 waves, 2 blocks/CU, XCD swizzle) ----------------
__global__ __launch_bounds__(512, 2) void attn_kernel(
    const ushort* __restrict__ Kf,   // [b][2048][160]
    const ushort* __restrict__ VfT,  // [b][288][2048]
    const ushort* __restrict__ Qf,   // [bh][2048][160] (scaled)
    float* __restrict__ Hf)          // [b][q][h][288]
{
  __shared__ ushort kL[KTL*KLP];
  __shared__ ushort vtL[DV*KTL];

  const int NT = NQL/QT;             // 16; grid = 512 blocks
  // XCD-chunked swizzle (bijective: 512 % 8 == 0, chunk = 64):
  // each XCD gets 64 consecutive logical blocks = 4 heads of one batch.
  int bid = blockIdx.x;
  int swz = (bid & 7) * 64 + (bid >> 3);
  int bh = swz / NT;
  int qt = swz - bh*NT;
  int b = bh >> 3, h = bh & 7;
  int t = threadIdx.x, w = t >> 6, l = t & 63;
  int ql = l & 15, g = l >> 4;

  const ushort* qrow = Qf + ((size_t)bh*NQL + (size_t)qt*QT + w*16 + ql)*DQK + g*8;
  short8 qf[5];
#pragma unroll
  for (int ks = 0; ks < 5; ks++)
    qf[ks] = *(const short8*)(qrow + ks*32);

  f32x4 oA[18];
#pragma unroll
  for (int i = 0; i < 18; i++) oA[i] = (f32x4)(0.f);
  float m = -INFINITY, lsum = 0.f;

  const ushort* kb = Kf  + (size_t)b*NKVL*DQK;
  const ushort* vb = VfT + (size_t)b*DV*NKVL;

  for (int kt0 = 0; kt0 < NKVL; kt0 += KTL) {
    // stage K tile: 1280 16B-chunks over 512 threads
#pragma unroll
    for (int it = 0; it < 3; it++) {
      int i = t + it*512;
      if (i < 1280) {
        int r = i / 20, c = i - r*20;
        int4v val = *(const int4v*)(kb + (size_t)(kt0 + r)*DQK + c*8);
        *(int4v*)(kL + r*KLP + c*8) = val;
      }
    }
    // stage V^T tile: 2304 chunks; XOR swizzle
#pragma unroll
    for (int it = 0; it < 5; it++) {
      int i = t + it*512;
      if (i < 2304) {
        int d = i >> 3, c = i & 7;
        int4v val = *(const int4v*)(vb + (size_t)d*NKVL + kt0 + c*8);
        int col = (c*8) ^ ((d & 7) << 3);
        *(int4v*)(vtL + d*64 + col) = val;
      }
    }
    __syncthreads();

    // scores S^T: 4 tiles (16kv x 16q)
    f32x4 sA[4];
    __builtin_amdgcn_s_setprio(1);
#pragma unroll
    for (int kvb = 0; kvb < 4; kvb++) {
      sA[kvb] = (f32x4)(0.f);
      const ushort* krow = kL + (ql + 16*kvb)*KLP + g*8;
#pragma unroll
      for (int ks = 0; ks < 5; ks++) {
        short8 kf = *(const short8*)(krow + ks*32);
        sA[kvb] = __builtin_amdgcn_mfma_f32_16x16x32_bf16(kf, qf[ks], sA[kvb], 0, 0, 0);
      }
    }
    __builtin_amdgcn_s_setprio(0);

    // online softmax with defer-rescale (T13, THR=8)
    float tm = sA[0][0];
#pragma unroll
    for (int kvb = 0; kvb < 4; kvb++)
#pragma unroll
      for (int r = 0; r < 4; r++) tm = fmaxf(tm, sA[kvb][r]);
    tm = fmaxf(tm, __shfl_xor(tm, 16));
    tm = fmaxf(tm, __shfl_xor(tm, 32));
    if (!__all(tm - m <= 8.0f)) {
      float nm = fmaxf(m, tm);
      float ef = __expf(m - nm);    // first tile: exp(-inf) = 0
      lsum *= ef;
#pragma unroll
      for (int i = 0; i < 18; i++) {
        oA[i][0] *= ef; oA[i][1] *= ef; oA[i][2] *= ef; oA[i][3] *= ef;
      }
      m = nm;
    }
    float rs = 0.f;
#pragma unroll
    for (int kvb = 0; kvb < 4; kvb++)
#pragma unroll
      for (int r = 0; r < 4; r++) {
        float p = __expf(sA[kvb][r] - m);
        sA[kvb][r] = p;
        rs += p;
      }
    rs += __shfl_xor(rs, 16);
    rs += __shfl_xor(rs, 32);
    lsum += rs;

    // pack P -> bf16 pairs
    unsigned int pk[4][2];
#pragma unroll
    for (int b2 = 0; b2 < 4; b2++)
#pragma unroll
      for (int p2 = 0; p2 < 2; p2++) {
        float lo = sA[b2][2*p2], hi = sA[b2][2*p2+1];
        unsigned int r_;
        asm("v_cvt_pk_bf16_f32 %0, %1, %2" : "=v"(r_) : "v"(lo), "v"(hi));
        pk[b2][p2] = r_;
      }

    int src0 = ql + ((l >> 4) & 1) * 32;
    int src1 = src0 + 16;
    bool hi_half = (l & 32) != 0;
#pragma unroll
    for (int s = 0; s < 2; s++) {
      unsigned int a0 = __shfl((int)pk[2*s][0], src0);
      unsigned int a1 = __shfl((int)pk[2*s][1], src0);
      unsigned int a2 = __shfl((int)pk[2*s][0], src1);
      unsigned int a3 = __shfl((int)pk[2*s][1], src1);
      unsigned int c0 = __shfl((int)pk[2*s+1][0], src0);
      unsigned int c1 = __shfl((int)pk[2*s+1][1], src0);
      unsigned int c2 = __shfl((int)pk[2*s+1][0], src1);
      unsigned int c3 = __shfl((int)pk[2*s+1][1], src1);
      union { unsigned int u[4]; short8 s8; } pf;
      pf.u[0] = hi_half ? c0 : a0;
      pf.u[1] = hi_half ? c1 : a1;
      pf.u[2] = hi_half ? c2 : a2;
      pf.u[3] = hi_half ? c3 : a3;
      __builtin_amdgcn_s_setprio(1);
#pragma unroll
      for (int db = 0; db < 18; db++) {
        int d = ql + 16*db;
        int col = (32*s + 8*g) ^ ((d & 7) << 3);
        short8 vf = *(const short8*)(vtL + d*64 + col);
        oA[db] = __builtin_amdgcn_mfma_f32_16x16x32_bf16(vf, pf.s8, oA[db], 0, 0, 0);
      }
      __builtin_amdgcn_s_setprio(0);
    }
    __syncthreads();
  }

  float inv = 1.0f / lsum;
  int q = qt*QT + w*16 + ql;
  float* orow = Hf + (((size_t)b*NQL + q)*HN + h)*DV;
#pragma unroll
  for (int db = 0; db < 18; db++) {
    float4 st = make_float4(oA[db][0]*inv, oA[db][1]*inv, oA[db][2]*inv, oA[db][3]*inv);
    *(float4*)(orow + 16*db + 4*g) = st;
  }
}

// ---------------- O-weight transpose prep ----------------
#define OWT_SZ 34816
__global__ __launch_bounds__(256) void prep_ow_kernel(
    const float* __restrict__ ow_mv, const float* __restrict__ ow_s2mv,
    const float* __restrict__ ow_mv2s, const float* __restrict__ ow_s2s,
    float* __restrict__ owT)
{
  int i = blockIdx.x*256 + threadIdx.x;
  if (i < 18432) {
    int y = i / 2048, r = i & 2047, ch = r >> 4, o = r & 15;
    owT[i] = ow_mv[(size_t)(o*128 + ch)*9 + y];
  } else if (i < 22528) {
    int r = i - 18432, jj = r >> 4, o = r & 15;
    owT[i] = ow_s2mv[o*256 + jj];
  } else if (i < 26624) {
    int r = i - 22528, ch = r >> 5, si = r & 31;
    owT[i] = ow_mv2s[si*128 + ch];
  } else if (i < OWT_SZ) {
    int r = i - 26624, jj = r >> 5, si = r & 31;
    owT[i] = ow_s2s[si*256 + jj];
  }
}

// ---------------- Output projection (coalesced transposed weights) ----------------
#define HSTR 2308
__global__ __launch_bounds__(256) void proj_o_kernel(
    const float* __restrict__ Hf,
    const float* __restrict__ owT,
    const float* __restrict__ ob_mv, const float* __restrict__ ob_s,
    float* __restrict__ outp)
{
  __shared__ float hL[8*HSTR];
  int t = threadIdx.x;
  int p0 = blockIdx.x * 8;
  for (int i = t; i < 8*2304/4; i += 256) {
    int idx = i*4; int p = idx / 2304; int c = idx - p*2304;
    *(float4*)(hL + p*HSTR + c) = *(const float4*)(Hf + (size_t)(p0 + p)*2304 + c);
  }
  __syncthreads();

  const float* mvT   = owT;            // [y][ch][o]: y*2048 + ch*16 + o
  const float* s2mvT = owT + 18432;    // jj*16 + o
  const float* mv2sT = owT + 22528;    // ch*32 + si
  const float* s2sT  = owT + 26624;    // jj*32 + si

  int o = t & 15, pp = (t >> 4) & 7, half = t >> 7;
  const float* x = hL + pp*HSTR;
  float acc[8];
#pragma unroll
  for (int a = 0; a < 8; a++) acc[a] = 0.f;
  if (half == 0) acc[0] = ob_mv[o];

  if (half == 0) {
    for (int ch = 0; ch < 128; ch++) {
      const float* xc = x + (ch >> 4)*288 + (ch & 15)*16;
      float w0 = mvT[0*2048 + ch*16 + o], w1 = mvT[1*2048 + ch*16 + o];
      float w2 = mvT[2*2048 + ch*16 + o];
      float w5 = mvT[5*2048 + ch*16 + o], w6 = mvT[6*2048 + ch*16 + o];
      float x0 = xc[0], x1 = xc[1], x2 = xc[2], x3 = xc[3];
      float x4 = xc[4], x5 = xc[5], x6 = xc[6], x7 = xc[7];
      acc[0] += w0*x0;
      acc[1] += w1*x1 + w5*x0;
      acc[2] += w1*x2;
      acc[3] += w1*x3;
      acc[4] += w1*x4;
      acc[5] += w2*x5 + w6*x2;
      acc[6] += w2*x6 + w6*x3;
      acc[7] += w2*x7 + w6*x4;
    }
    for (int jj = 0; jj < 256; jj++)
      acc[0] += s2mvT[jj*16 + o] * x[(jj >> 5)*288 + 256 + (jj & 31)];
  } else {
    for (int ch = 0; ch < 128; ch++) {
      const float* xc = x + (ch >> 4)*288 + (ch & 15)*16 + 8;
      float w2 = mvT[2*2048 + ch*16 + o], w3 = mvT[3*2048 + ch*16 + o];
      float w4 = mvT[4*2048 + ch*16 + o];
      float w7 = mvT[7*2048 + ch*16 + o], w8 = mvT[8*2048 + ch*16 + o];
      float x8 = xc[0], x9 = xc[1], x10 = xc[2], x11 = xc[3];
      float x12 = xc[4], x13 = xc[5], x14 = xc[6], x15 = xc[7];
      acc[0] += w2*x8;
      acc[1] += w2*x9;
      acc[2] += w2*x10;
      acc[3] += w3*x11 + w7*x8;
      acc[4] += w3*x12 + w7*x9;
      acc[5] += w3*x13 + w7*x10;
      acc[6] += w3*x14;
      acc[7] += w4*x15 + w8*x14;
    }
  }

  float* od = outp + (size_t)(p0 + pp)*256 + o*16 + half*8;
  *(float4*)(od)     = make_float4(acc[0], acc[1], acc[2], acc[3]);
  *(float4*)(od + 4) = make_float4(acc[4], acc[5], acc[6], acc[7]);

  // scalar outputs
  int si = t & 31, ps = t >> 5;
  const float* xs = hL + ps*HSTR;
  float vs = ob_s[si];
  for (int ch = 0; ch < 128; ch++)
    vs += mv2sT[ch*32 + si] * xs[(ch >> 4)*288 + (ch & 15)*16];
  for (int jj = 0; jj < 256; jj++)
    vs += s2sT[jj*32 + si] * xs[(jj >> 5)*288 + 256 + (jj & 31)];
  float* out_s = outp + (size_t)NB*NQL*256;
  out_s[(size_t)(p0 + ps)*32 + si] = vs;
}

extern "C" void kernel_launch(void* const* d_in, const int* in_sizes, int n_in,
                              void* d_out, int out_size, void* d_ws, size_t ws_size,
                              hipStream_t stream)
{
  const float* mv_kv = (const float*)d_in[0];
  const float* mv_q  = (const float*)d_in[1];
  const float* s_kv  = (const float*)d_in[2];
  const float* s_q   = (const float*)d_in[3];

  ushort* Kf  = (ushort*)d_ws;                          // 4*2048*160   bf16
  ushort* VfT = Kf  + (size_t)NB*NKVL*DQK;              // 4*288*2048   bf16
  ushort* Qf  = VfT + (size_t)NB*DV*NKVL;               // 4*8*2048*160 bf16
  float*  Hf  = (float*)(Qf + (size_t)NB*HN*NQL*DQK);   // 4*2048*8*288 f32
  float*  owT = Hf + (size_t)NB*NQL*HN*DV;              // 34816 f32

  prep_ow_kernel<<<(OWT_SZ + 255)/256, 256, 0, stream>>>(
      (const float*)d_in[22], (const float*)d_in[23],
      (const float*)d_in[25], (const float*)d_in[26], owT);
  proj_kv_kernel<<<NB*NKVL/32, 256, 0, stream>>>(mv_kv, s_kv,
      (const float*)d_in[10], (const float*)d_in[11], (const float*)d_in[12],
      (const float*)d_in[13], (const float*)d_in[14], (const float*)d_in[15],
      (const float*)d_in[16], (const float*)d_in[17], (const float*)d_in[18],
      (const float*)d_in[19], (const float*)d_in[20], (const float*)d_in[21],
      Kf, VfT);
  proj_q_kernel<<<NB*NQL/16, 320, 0, stream>>>(mv_q, s_q,
      (const float*)d_in[4], (const float*)d_in[5], (const float*)d_in[6],
      (const float*)d_in[7], (const float*)d_in[8], (const float*)d_in[9],
      Qf);
  attn_kernel<<<NB*HN*(NQL/QT), 512, 0, stream>>>(Kf, VfT, Qf, Hf);
  proj_o_kernel<<<NB*NQL/8, 256, 0, stream>>>(Hf, owT,
      (const float*)d_in[24], (const float*)d_in[27],
      (float*)d_out);
}